// Round 1
// baseline (2292.157 us; speedup 1.0000x reference)
//
#include <hip/hip_runtime.h>
#include <cstddef>

// Problem constants (match reference)
#define DMODEL 1024
#define DI     2048      // D_INNER
#define LSEQ   2048
#define NB     2
#define DSTATE 16
#define DTRANK 64
#define NXP    96        // DT_RANK + 2*D_STATE
#define MROWS  (NB*LSEQ) // 4096 GEMM rows

__device__ __forceinline__ float silu_f(float v) {
  return v / (1.f + __expf(-v));
}
__device__ __forceinline__ float softplus_f(float v) {
  return (v > 20.f) ? v : log1pf(__expf(v));
}

// C[m,n] = act( sum_k A[m*lda+k] * B[n*ldb+k] (+ bias[n]) )
// M implied by gridDim.y*128 (must divide exactly); N guarded; K % 16 == 0.
// 128x128 tile, 256 threads, 8x8 per thread, BK=16.
template<int ACT>
__global__ __launch_bounds__(256)
void gemm_nt(const float* __restrict__ A, const float* __restrict__ B,
             const float* __restrict__ bias, float* __restrict__ C,
             int N, int K, int lda, int ldb, int ldc) {
  __shared__ float As[16][132];  // [k][m], pad 132 keeps float4 row alignment
  __shared__ float Bs[16][132];
  const int tid = threadIdx.x;
  const int bm = blockIdx.y * 128, bn = blockIdx.x * 128;
  const int r  = tid >> 2;           // 0..63
  const int c4 = (tid & 3) << 2;     // 0,4,8,12
  const int ty = tid >> 4, tx = tid & 15;
  float acc[8][8];
  #pragma unroll
  for (int i = 0; i < 8; ++i)
    #pragma unroll
    for (int j = 0; j < 8; ++j) acc[i][j] = 0.f;

  for (int k0 = 0; k0 < K; k0 += 16) {
    float4 a0 = *(const float4*)(A + (size_t)(bm + r) * lda + k0 + c4);
    float4 a1 = *(const float4*)(A + (size_t)(bm + r + 64) * lda + k0 + c4);
    float4 b0 = make_float4(0.f, 0.f, 0.f, 0.f);
    float4 b1 = make_float4(0.f, 0.f, 0.f, 0.f);
    if (bn + r < N)      b0 = *(const float4*)(B + (size_t)(bn + r) * ldb + k0 + c4);
    if (bn + r + 64 < N) b1 = *(const float4*)(B + (size_t)(bn + r + 64) * ldb + k0 + c4);
    As[c4+0][r]    = a0.x; As[c4+1][r]    = a0.y; As[c4+2][r]    = a0.z; As[c4+3][r]    = a0.w;
    As[c4+0][r+64] = a1.x; As[c4+1][r+64] = a1.y; As[c4+2][r+64] = a1.z; As[c4+3][r+64] = a1.w;
    Bs[c4+0][r]    = b0.x; Bs[c4+1][r]    = b0.y; Bs[c4+2][r]    = b0.z; Bs[c4+3][r]    = b0.w;
    Bs[c4+0][r+64] = b1.x; Bs[c4+1][r+64] = b1.y; Bs[c4+2][r+64] = b1.z; Bs[c4+3][r+64] = b1.w;
    __syncthreads();
    #pragma unroll
    for (int k = 0; k < 16; ++k) {
      float4 av0 = *(const float4*)&As[k][ty*4];
      float4 av1 = *(const float4*)&As[k][64 + ty*4];
      float4 bv0 = *(const float4*)&Bs[k][tx*4];
      float4 bv1 = *(const float4*)&Bs[k][64 + tx*4];
      float a[8] = {av0.x, av0.y, av0.z, av0.w, av1.x, av1.y, av1.z, av1.w};
      float b[8] = {bv0.x, bv0.y, bv0.z, bv0.w, bv1.x, bv1.y, bv1.z, bv1.w};
      #pragma unroll
      for (int i = 0; i < 8; ++i)
        #pragma unroll
        for (int j = 0; j < 8; ++j)
          acc[i][j] = fmaf(a[i], b[j], acc[i][j]);
    }
    __syncthreads();
  }
  #pragma unroll
  for (int i = 0; i < 8; ++i) {
    const int m = bm + ty * 4 + (i & 3) + ((i >= 4) ? 64 : 0);
    #pragma unroll
    for (int j = 0; j < 8; ++j) {
      const int n = bn + tx * 4 + (j & 3) + ((j >= 4) ? 64 : 0);
      if (n < N) {
        float v = acc[i][j];
        if (ACT == 1) v = softplus_f(v + bias[n]);
        C[(size_t)m * ldc + n] = v;
      }
    }
  }
}

// Causal depthwise conv (width 4) + bias + SiLU.  xc2[b,l,d]
__global__ __launch_bounds__(256)
void conv_silu_kernel(const float* __restrict__ xc_raw, const float* __restrict__ cw,
                      const float* __restrict__ cb, float* __restrict__ xc2) {
  const int idx = blockIdx.x * 256 + threadIdx.x;
  const int d = idx & (DI - 1);
  const int l = (idx >> 11) & (LSEQ - 1);
  const int b = idx >> 22;
  float acc = cb[d];
  #pragma unroll
  for (int j = 0; j < 4; ++j) {
    const int ls = l - 3 + j;
    if (ls >= 0)
      acc = fmaf(xc_raw[((size_t)b * LSEQ + ls) * DI + d], cw[d * 4 + j], acc);
  }
  xc2[idx] = silu_f(acc);
}

// Selective scan: one thread per (b,d) channel, 16 states in registers.
// Sequential over L; B_t/C_t (wave-uniform) staged in LDS 64 steps at a time.
// Fuses epilogue: y = (scan_y + xc*D) * silu(z).
__global__ __launch_bounds__(256)
void scan_kernel(const float* __restrict__ xc2, const float* __restrict__ dtb,
                 const float* __restrict__ xp, const float* __restrict__ z,
                 const float* __restrict__ A_log, const float* __restrict__ Dp,
                 float* __restrict__ y) {
  const int b = blockIdx.y;
  const int d = blockIdx.x * 256 + threadIdx.x;
  float A[DSTATE], h[DSTATE];
  #pragma unroll
  for (int n = 0; n < DSTATE; ++n) {
    A[n] = -__expf(A_log[(size_t)d * DSTATE + n]);
    h[n] = 0.f;
  }
  const float Dd = Dp[d];
  __shared__ float sbc[64][32];   // per timestep: [0:16)=B, [16:32)=C
  const float* xpb = xp + (size_t)b * LSEQ * NXP;

  for (int t0 = 0; t0 < LSEQ; t0 += 64) {
    __syncthreads();
    for (int i = threadIdx.x; i < 64 * 32; i += 256) {
      const int row = i >> 5, col = i & 31;
      sbc[row][col] = xpb[(size_t)(t0 + row) * NXP + DTRANK + col];
    }
    __syncthreads();
    for (int tt = 0; tt < 64; ++tt) {
      const int t = t0 + tt;
      const size_t base = ((size_t)b * LSEQ + t) * DI + d;
      const float dtv = dtb[base];
      const float xv  = xc2[base];
      const float dx  = dtv * xv;
      float yv = 0.f;
      #pragma unroll
      for (int n = 0; n < DSTATE; ++n) {
        const float ab = __expf(dtv * A[n]);
        h[n] = fmaf(ab, h[n], dx * sbc[tt][n]);
        yv = fmaf(h[n], sbc[tt][DSTATE + n], yv);
      }
      const float zv = z[base];
      y[base] = (yv + xv * Dd) * silu_f(zv);
    }
  }
}

extern "C" void kernel_launch(void* const* d_in, const int* in_sizes, int n_in,
                              void* d_out, int out_size, void* d_ws, size_t ws_size,
                              hipStream_t stream) {
  const float* x      = (const float*)d_in[0];
  const float* W_in   = (const float*)d_in[1];
  const float* conv_w = (const float*)d_in[2];
  const float* conv_b = (const float*)d_in[3];
  const float* W_xproj= (const float*)d_in[4];
  const float* W_dt   = (const float*)d_in[5];
  const float* b_dt   = (const float*)d_in[6];
  const float* A_log  = (const float*)d_in[7];
  const float* Dp     = (const float*)d_in[8];
  const float* W_out  = (const float*)d_in[9];
  float* out = (float*)d_out;
  float* ws  = (float*)d_ws;

  // ws layout (floats): xc_raw (reused as y) | z | xc2 | dt | xp  => ~136 MB
  const size_t SEG = (size_t)NB * LSEQ * DI;     // 8,388,608
  float* xc_raw = ws;                 // pre-conv xc; later reused as y
  float* zbuf   = ws + SEG;
  float* xc2    = ws + 2 * SEG;
  float* dtb    = ws + 3 * SEG;
  float* xp     = ws + 4 * SEG;       // 4096*96

  dim3 blk(256);

  // GEMM1: xz = x @ W_in^T, split into xc (rows 0..2047 of W_in) and z
  gemm_nt<0><<<dim3(DI/128, MROWS/128), blk, 0, stream>>>(
      x, W_in,                    nullptr, xc_raw, DI, DMODEL, DMODEL, DMODEL, DI);
  gemm_nt<0><<<dim3(DI/128, MROWS/128), blk, 0, stream>>>(
      x, W_in + (size_t)DI*DMODEL, nullptr, zbuf,  DI, DMODEL, DMODEL, DMODEL, DI);

  // conv + bias + SiLU
  conv_silu_kernel<<<(NB*LSEQ*DI)/256, blk, 0, stream>>>(xc_raw, conv_w, conv_b, xc2);

  // GEMM2: xp = xc2 @ W_xproj^T  (N=96, guarded)
  gemm_nt<0><<<dim3(1, MROWS/128), blk, 0, stream>>>(
      xc2, W_xproj, nullptr, xp, NXP, DI, DI, DI, NXP);

  // GEMM3: dt = softplus(dt_lr @ W_dt^T + b_dt)   (A = xp[:, :64], lda=96)
  gemm_nt<1><<<dim3(DI/128, MROWS/128), blk, 0, stream>>>(
      xp, W_dt, b_dt, dtb, DI, DTRANK, NXP, DTRANK, DI);

  // scan + fused epilogue  -> y into xc_raw buffer (no longer needed)
  scan_kernel<<<dim3(DI/256, NB), blk, 0, stream>>>(
      xc2, dtb, xp, zbuf, A_log, Dp, xc_raw);

  // GEMM4: out = y @ W_out^T
  gemm_nt<0><<<dim3(DMODEL/128, MROWS/128), blk, 0, stream>>>(
      xc_raw, W_out, nullptr, out, DMODEL, DI, DI, DI, DMODEL);
}

// Round 2
// 1758.101 us; speedup vs baseline: 1.3038x; 1.3038x over previous
//
#include <hip/hip_runtime.h>
#include <cstddef>

// Problem constants (match reference)
#define DMODEL 1024
#define DI     2048      // D_INNER
#define LSEQ   2048
#define NB     2
#define DSTATE 16
#define DTRANK 64
#define NXP    96        // DT_RANK + 2*D_STATE
#define MROWS  (NB*LSEQ) // 4096 GEMM rows

__device__ __forceinline__ float silu_f(float v) {
  return v / (1.f + __expf(-v));
}
__device__ __forceinline__ float softplus_f(float v) {
  return (v > 20.f) ? v : log1pf(__expf(v));
}

// C[m,n] = act( sum_k A[m*lda+k] * B[n*ldb+k] (+ bias[n]) )
// M implied by gridDim.y*128 (must divide exactly); N guarded; K % 16 == 0.
// 128x128 tile, 256 threads, 8x8 per thread, BK=16.
template<int ACT>
__global__ __launch_bounds__(256)
void gemm_nt(const float* __restrict__ A, const float* __restrict__ B,
             const float* __restrict__ bias, float* __restrict__ C,
             int N, int K, int lda, int ldb, int ldc) {
  __shared__ float As[16][132];  // [k][m], pad 132 keeps float4 row alignment
  __shared__ float Bs[16][132];
  const int tid = threadIdx.x;
  const int bm = blockIdx.y * 128, bn = blockIdx.x * 128;
  const int r  = tid >> 2;           // 0..63
  const int c4 = (tid & 3) << 2;     // 0,4,8,12
  const int ty = tid >> 4, tx = tid & 15;
  float acc[8][8];
  #pragma unroll
  for (int i = 0; i < 8; ++i)
    #pragma unroll
    for (int j = 0; j < 8; ++j) acc[i][j] = 0.f;

  for (int k0 = 0; k0 < K; k0 += 16) {
    float4 a0 = *(const float4*)(A + (size_t)(bm + r) * lda + k0 + c4);
    float4 a1 = *(const float4*)(A + (size_t)(bm + r + 64) * lda + k0 + c4);
    float4 b0 = make_float4(0.f, 0.f, 0.f, 0.f);
    float4 b1 = make_float4(0.f, 0.f, 0.f, 0.f);
    if (bn + r < N)      b0 = *(const float4*)(B + (size_t)(bn + r) * ldb + k0 + c4);
    if (bn + r + 64 < N) b1 = *(const float4*)(B + (size_t)(bn + r + 64) * ldb + k0 + c4);
    As[c4+0][r]    = a0.x; As[c4+1][r]    = a0.y; As[c4+2][r]    = a0.z; As[c4+3][r]    = a0.w;
    As[c4+0][r+64] = a1.x; As[c4+1][r+64] = a1.y; As[c4+2][r+64] = a1.z; As[c4+3][r+64] = a1.w;
    Bs[c4+0][r]    = b0.x; Bs[c4+1][r]    = b0.y; Bs[c4+2][r]    = b0.z; Bs[c4+3][r]    = b0.w;
    Bs[c4+0][r+64] = b1.x; Bs[c4+1][r+64] = b1.y; Bs[c4+2][r+64] = b1.z; Bs[c4+3][r+64] = b1.w;
    __syncthreads();
    #pragma unroll
    for (int k = 0; k < 16; ++k) {
      float4 av0 = *(const float4*)&As[k][ty*4];
      float4 av1 = *(const float4*)&As[k][64 + ty*4];
      float4 bv0 = *(const float4*)&Bs[k][tx*4];
      float4 bv1 = *(const float4*)&Bs[k][64 + tx*4];
      float a[8] = {av0.x, av0.y, av0.z, av0.w, av1.x, av1.y, av1.z, av1.w};
      float b[8] = {bv0.x, bv0.y, bv0.z, bv0.w, bv1.x, bv1.y, bv1.z, bv1.w};
      #pragma unroll
      for (int i = 0; i < 8; ++i)
        #pragma unroll
        for (int j = 0; j < 8; ++j)
          acc[i][j] = fmaf(a[i], b[j], acc[i][j]);
    }
    __syncthreads();
  }
  #pragma unroll
  for (int i = 0; i < 8; ++i) {
    const int m = bm + ty * 4 + (i & 3) + ((i >= 4) ? 64 : 0);
    #pragma unroll
    for (int j = 0; j < 8; ++j) {
      const int n = bn + tx * 4 + (j & 3) + ((j >= 4) ? 64 : 0);
      if (n < N) {
        float v = acc[i][j];
        if (ACT == 1) v = softplus_f(v + bias[n]);
        C[(size_t)m * ldc + n] = v;
      }
    }
  }
}

// Causal depthwise conv (width 4) + bias + SiLU.  xc2[b,l,d]
__global__ __launch_bounds__(256)
void conv_silu_kernel(const float* __restrict__ xc_raw, const float* __restrict__ cw,
                      const float* __restrict__ cb, float* __restrict__ xc2) {
  const int idx = blockIdx.x * 256 + threadIdx.x;
  const int d = idx & (DI - 1);
  const int l = (idx >> 11) & (LSEQ - 1);
  const int b = idx >> 22;
  float acc = cb[d];
  #pragma unroll
  for (int j = 0; j < 4; ++j) {
    const int ls = l - 3 + j;
    if (ls >= 0)
      acc = fmaf(xc_raw[((size_t)b * LSEQ + ls) * DI + d], cw[d * 4 + j], acc);
  }
  xc2[idx] = silu_f(acc);
}

// Selective scan v2: 16 lanes per (b,d) channel — one lane per state n.
// h-recurrence is independent per n; y_t = sum_n h[n]*C[n] via 4x shfl_xor.
// Software-pipelined: next 8 timesteps' loads issued while computing current 8.
// Fuses epilogue: y = (scan_y + xc*D) * silu(z).
__global__ __launch_bounds__(256)
void scan_kernel(const float* __restrict__ xc2, const float* __restrict__ dtb,
                 const float* __restrict__ xp, const float* __restrict__ z,
                 const float* __restrict__ A_log, const float* __restrict__ Dp,
                 float* __restrict__ y) {
  const int b   = blockIdx.y;
  const int lane = threadIdx.x & 63;
  const int wv   = threadIdx.x >> 6;    // wave in block: 0..3
  const int n    = lane & 15;           // state index
  const int dl   = lane >> 4;           // channel-within-wave: 0..3
  const int d    = blockIdx.x * 16 + wv * 4 + dl;

  const float An = -__expf(A_log[(size_t)d * DSTATE + n]);
  const float Dd = Dp[d];
  float h = 0.f;

  const float* xpb = xp + (size_t)b * LSEQ * NXP + DTRANK;
  const size_t cbase = (size_t)b * LSEQ * DI + d;

  constexpr int U = 8;
  float cdt[U], cx[U], cB[U], cC[U], cz[U];
  float ndt[U], nx[U], nB[U], nC[U], nz[U];

  #pragma unroll
  for (int u = 0; u < U; ++u) {
    const size_t base = cbase + (size_t)u * DI;
    cdt[u] = dtb[base];
    cx[u]  = xc2[base];
    cz[u]  = z[base];
    cB[u]  = xpb[(size_t)u * NXP + n];
    cC[u]  = xpb[(size_t)u * NXP + DSTATE + n];
  }

  for (int t0 = 0; t0 < LSEQ; t0 += U) {
    const int t1 = t0 + U;
    if (t1 < LSEQ) {
      #pragma unroll
      for (int u = 0; u < U; ++u) {
        const size_t base = cbase + (size_t)(t1 + u) * DI;
        ndt[u] = dtb[base];
        nx[u]  = xc2[base];
        nz[u]  = z[base];
        nB[u]  = xpb[(size_t)(t1 + u) * NXP + n];
        nC[u]  = xpb[(size_t)(t1 + u) * NXP + DSTATE + n];
      }
    }
    #pragma unroll
    for (int u = 0; u < U; ++u) {
      const float dtv = cdt[u];
      const float ab  = __expf(dtv * An);
      h = fmaf(ab, h, dtv * cx[u] * cB[u]);
      float part = h * cC[u];
      part += __shfl_xor(part, 1, 64);
      part += __shfl_xor(part, 2, 64);
      part += __shfl_xor(part, 4, 64);
      part += __shfl_xor(part, 8, 64);
      if (n == 0) {
        y[cbase + (size_t)(t0 + u) * DI] = (part + cx[u] * Dd) * silu_f(cz[u]);
      }
    }
    #pragma unroll
    for (int u = 0; u < U; ++u) {
      cdt[u] = ndt[u]; cx[u] = nx[u]; cB[u] = nB[u]; cC[u] = nC[u]; cz[u] = nz[u];
    }
  }
}

extern "C" void kernel_launch(void* const* d_in, const int* in_sizes, int n_in,
                              void* d_out, int out_size, void* d_ws, size_t ws_size,
                              hipStream_t stream) {
  const float* x      = (const float*)d_in[0];
  const float* W_in   = (const float*)d_in[1];
  const float* conv_w = (const float*)d_in[2];
  const float* conv_b = (const float*)d_in[3];
  const float* W_xproj= (const float*)d_in[4];
  const float* W_dt   = (const float*)d_in[5];
  const float* b_dt   = (const float*)d_in[6];
  const float* A_log  = (const float*)d_in[7];
  const float* Dp     = (const float*)d_in[8];
  const float* W_out  = (const float*)d_in[9];
  float* out = (float*)d_out;
  float* ws  = (float*)d_ws;

  // ws layout (floats): xc_raw (reused as y) | z | xc2 | dt | xp  => ~136 MB
  const size_t SEG = (size_t)NB * LSEQ * DI;     // 8,388,608
  float* xc_raw = ws;                 // pre-conv xc; later reused as y
  float* zbuf   = ws + SEG;
  float* xc2    = ws + 2 * SEG;
  float* dtb    = ws + 3 * SEG;
  float* xp     = ws + 4 * SEG;       // 4096*96

  dim3 blk(256);

  // GEMM1: xz = x @ W_in^T, split into xc (rows 0..2047 of W_in) and z
  gemm_nt<0><<<dim3(DI/128, MROWS/128), blk, 0, stream>>>(
      x, W_in,                    nullptr, xc_raw, DI, DMODEL, DMODEL, DMODEL, DI);
  gemm_nt<0><<<dim3(DI/128, MROWS/128), blk, 0, stream>>>(
      x, W_in + (size_t)DI*DMODEL, nullptr, zbuf,  DI, DMODEL, DMODEL, DMODEL, DI);

  // conv + bias + SiLU
  conv_silu_kernel<<<(NB*LSEQ*DI)/256, blk, 0, stream>>>(xc_raw, conv_w, conv_b, xc2);

  // GEMM2: xp = xc2 @ W_xproj^T  (N=96, guarded)
  gemm_nt<0><<<dim3(1, MROWS/128), blk, 0, stream>>>(
      xc2, W_xproj, nullptr, xp, NXP, DI, DI, DI, NXP);

  // GEMM3: dt = softplus(dt_lr @ W_dt^T + b_dt)   (A = xp[:, :64], lda=96)
  gemm_nt<1><<<dim3(DI/128, MROWS/128), blk, 0, stream>>>(
      xp, W_dt, b_dt, dtb, DI, DTRANK, NXP, DTRANK, DI);

  // scan + fused epilogue  -> y into xc_raw buffer (no longer needed)
  scan_kernel<<<dim3(DI/16, NB), blk, 0, stream>>>(
      xc2, dtb, xp, zbuf, A_log, Dp, xc_raw);

  // GEMM4: out = y @ W_out^T
  gemm_nt<0><<<dim3(DMODEL/128, MROWS/128), blk, 0, stream>>>(
      xc_raw, W_out, nullptr, out, DMODEL, DI, DI, DI, DMODEL);
}

// Round 3
// 1214.958 us; speedup vs baseline: 1.8866x; 1.4470x over previous
//
#include <hip/hip_runtime.h>
#include <cstddef>

// Problem constants (match reference)
#define DMODEL 1024
#define DI     2048      // D_INNER
#define LSEQ   2048
#define NB     2
#define DSTATE 16
#define DTRANK 64
#define NXP    96        // DT_RANK + 2*D_STATE
#define MROWS  (NB*LSEQ) // 4096 GEMM rows
#define CHUNKS 8
#define LC     (LSEQ/CHUNKS)   // 256

__device__ __forceinline__ float silu_f(float v) {
  return v / (1.f + __expf(-v));
}
__device__ __forceinline__ float softplus_f(float v) {
  return (v > 20.f) ? v : log1pf(__expf(v));
}

// C[m,n] = act( sum_k A[m*lda+k] * B[n*ldb+k] (+ bias[n]) )
// 128x128 tile, 256 threads, 8x8 per thread, BK=16.
template<int ACT>
__global__ __launch_bounds__(256)
void gemm_nt(const float* __restrict__ A, const float* __restrict__ B,
             const float* __restrict__ bias, float* __restrict__ C,
             int N, int K, int lda, int ldb, int ldc) {
  __shared__ float As[16][132];
  __shared__ float Bs[16][132];
  const int tid = threadIdx.x;
  const int bm = blockIdx.y * 128, bn = blockIdx.x * 128;
  const int r  = tid >> 2;
  const int c4 = (tid & 3) << 2;
  const int ty = tid >> 4, tx = tid & 15;
  float acc[8][8];
  #pragma unroll
  for (int i = 0; i < 8; ++i)
    #pragma unroll
    for (int j = 0; j < 8; ++j) acc[i][j] = 0.f;

  for (int k0 = 0; k0 < K; k0 += 16) {
    float4 a0 = *(const float4*)(A + (size_t)(bm + r) * lda + k0 + c4);
    float4 a1 = *(const float4*)(A + (size_t)(bm + r + 64) * lda + k0 + c4);
    float4 b0 = make_float4(0.f, 0.f, 0.f, 0.f);
    float4 b1 = make_float4(0.f, 0.f, 0.f, 0.f);
    if (bn + r < N)      b0 = *(const float4*)(B + (size_t)(bn + r) * ldb + k0 + c4);
    if (bn + r + 64 < N) b1 = *(const float4*)(B + (size_t)(bn + r + 64) * ldb + k0 + c4);
    As[c4+0][r]    = a0.x; As[c4+1][r]    = a0.y; As[c4+2][r]    = a0.z; As[c4+3][r]    = a0.w;
    As[c4+0][r+64] = a1.x; As[c4+1][r+64] = a1.y; As[c4+2][r+64] = a1.z; As[c4+3][r+64] = a1.w;
    Bs[c4+0][r]    = b0.x; Bs[c4+1][r]    = b0.y; Bs[c4+2][r]    = b0.z; Bs[c4+3][r]    = b0.w;
    Bs[c4+0][r+64] = b1.x; Bs[c4+1][r+64] = b1.y; Bs[c4+2][r+64] = b1.z; Bs[c4+3][r+64] = b1.w;
    __syncthreads();
    #pragma unroll
    for (int k = 0; k < 16; ++k) {
      float4 av0 = *(const float4*)&As[k][ty*4];
      float4 av1 = *(const float4*)&As[k][64 + ty*4];
      float4 bv0 = *(const float4*)&Bs[k][tx*4];
      float4 bv1 = *(const float4*)&Bs[k][64 + tx*4];
      float a[8] = {av0.x, av0.y, av0.z, av0.w, av1.x, av1.y, av1.z, av1.w};
      float b[8] = {bv0.x, bv0.y, bv0.z, bv0.w, bv1.x, bv1.y, bv1.z, bv1.w};
      #pragma unroll
      for (int i = 0; i < 8; ++i)
        #pragma unroll
        for (int j = 0; j < 8; ++j)
          acc[i][j] = fmaf(a[i], b[j], acc[i][j]);
    }
    __syncthreads();
  }
  #pragma unroll
  for (int i = 0; i < 8; ++i) {
    const int m = bm + ty * 4 + (i & 3) + ((i >= 4) ? 64 : 0);
    #pragma unroll
    for (int j = 0; j < 8; ++j) {
      const int n = bn + tx * 4 + (j & 3) + ((j >= 4) ? 64 : 0);
      if (n < N) {
        float v = acc[i][j];
        if (ACT == 1) v = softplus_f(v + bias[n]);
        C[(size_t)m * ldc + n] = v;
      }
    }
  }
}

// Split-K GEMM: blockIdx.z selects a K-slice; epilogue atomicAdd (C pre-zeroed).
__global__ __launch_bounds__(256)
void gemm_nt_splitk(const float* __restrict__ A, const float* __restrict__ B,
                    float* __restrict__ C,
                    int N, int lda, int ldb, int ldc, int kslice) {
  __shared__ float As[16][132];
  __shared__ float Bs[16][132];
  const int tid = threadIdx.x;
  const int bm = blockIdx.y * 128, bn = blockIdx.x * 128;
  const int kbeg = blockIdx.z * kslice, kend = kbeg + kslice;
  const int r  = tid >> 2;
  const int c4 = (tid & 3) << 2;
  const int ty = tid >> 4, tx = tid & 15;
  float acc[8][8];
  #pragma unroll
  for (int i = 0; i < 8; ++i)
    #pragma unroll
    for (int j = 0; j < 8; ++j) acc[i][j] = 0.f;

  for (int k0 = kbeg; k0 < kend; k0 += 16) {
    float4 a0 = *(const float4*)(A + (size_t)(bm + r) * lda + k0 + c4);
    float4 a1 = *(const float4*)(A + (size_t)(bm + r + 64) * lda + k0 + c4);
    float4 b0 = make_float4(0.f, 0.f, 0.f, 0.f);
    float4 b1 = make_float4(0.f, 0.f, 0.f, 0.f);
    if (bn + r < N)      b0 = *(const float4*)(B + (size_t)(bn + r) * ldb + k0 + c4);
    if (bn + r + 64 < N) b1 = *(const float4*)(B + (size_t)(bn + r + 64) * ldb + k0 + c4);
    As[c4+0][r]    = a0.x; As[c4+1][r]    = a0.y; As[c4+2][r]    = a0.z; As[c4+3][r]    = a0.w;
    As[c4+0][r+64] = a1.x; As[c4+1][r+64] = a1.y; As[c4+2][r+64] = a1.z; As[c4+3][r+64] = a1.w;
    Bs[c4+0][r]    = b0.x; Bs[c4+1][r]    = b0.y; Bs[c4+2][r]    = b0.z; Bs[c4+3][r]    = b0.w;
    Bs[c4+0][r+64] = b1.x; Bs[c4+1][r+64] = b1.y; Bs[c4+2][r+64] = b1.z; Bs[c4+3][r+64] = b1.w;
    __syncthreads();
    #pragma unroll
    for (int k = 0; k < 16; ++k) {
      float4 av0 = *(const float4*)&As[k][ty*4];
      float4 av1 = *(const float4*)&As[k][64 + ty*4];
      float4 bv0 = *(const float4*)&Bs[k][tx*4];
      float4 bv1 = *(const float4*)&Bs[k][64 + tx*4];
      float a[8] = {av0.x, av0.y, av0.z, av0.w, av1.x, av1.y, av1.z, av1.w};
      float b[8] = {bv0.x, bv0.y, bv0.z, bv0.w, bv1.x, bv1.y, bv1.z, bv1.w};
      #pragma unroll
      for (int i = 0; i < 8; ++i)
        #pragma unroll
        for (int j = 0; j < 8; ++j)
          acc[i][j] = fmaf(a[i], b[j], acc[i][j]);
    }
    __syncthreads();
  }
  #pragma unroll
  for (int i = 0; i < 8; ++i) {
    const int m = bm + ty * 4 + (i & 3) + ((i >= 4) ? 64 : 0);
    #pragma unroll
    for (int j = 0; j < 8; ++j) {
      const int n = bn + tx * 4 + (j & 3) + ((j >= 4) ? 64 : 0);
      if (n < N) atomicAdd(&C[(size_t)m * ldc + n], acc[i][j]);
    }
  }
}

// Causal depthwise conv (width 4) + bias + SiLU.  xc2[b,l,d]
__global__ __launch_bounds__(256)
void conv_silu_kernel(const float* __restrict__ xc_raw, const float* __restrict__ cw,
                      const float* __restrict__ cb, float* __restrict__ xc2) {
  const int idx = blockIdx.x * 256 + threadIdx.x;
  const int d = idx & (DI - 1);
  const int l = (idx >> 11) & (LSEQ - 1);
  const int b = idx >> 22;
  float acc = cb[d];
  #pragma unroll
  for (int j = 0; j < 4; ++j) {
    const int ls = l - 3 + j;
    if (ls >= 0)
      acc = fmaf(xc_raw[((size_t)b * LSEQ + ls) * DI + d], cw[d * 4 + j], acc);
  }
  xc2[idx] = silu_f(acc);
}

// ---- Chunked selective scan ----
// Pass 1: per-chunk local scan with h0=0. 16 lanes per (b,d): one lane per state.
// Writes: y_local (into y buffer), cumdt (in-place over dtb), chunk-final h -> hloc,
// chunk dt total -> totdt.
__global__ __launch_bounds__(256, 8)
void scan_chunk_kernel(const float* __restrict__ xc2, float* __restrict__ dtb,
                       const float* __restrict__ xp, const float* __restrict__ A_log,
                       float* __restrict__ y_local, float* __restrict__ hloc,
                       float* __restrict__ totdt) {
  const int b    = blockIdx.y;
  const int c    = blockIdx.z;
  const int lane = threadIdx.x & 63;
  const int wv   = threadIdx.x >> 6;
  const int n    = lane & 15;
  const int dl   = lane >> 4;
  const int d    = blockIdx.x * 16 + wv * 4 + dl;

  const float An = -__expf(A_log[(size_t)d * DSTATE + n]);
  float h = 0.f, cum = 0.f;
  const int t0c = c * LC;
  const float* xpb = xp + ((size_t)b * LSEQ + t0c) * NXP + DTRANK;
  const size_t cbase = ((size_t)b * LSEQ + t0c) * DI + d;

  constexpr int U = 4;
  for (int g = 0; g < LC; g += U) {
    float cdt[U], cx[U], cB[U], cC[U];
    #pragma unroll
    for (int u = 0; u < U; ++u) {
      const size_t base = cbase + (size_t)(g + u) * DI;
      cdt[u] = dtb[base];
      cx[u]  = xc2[base];
      cB[u]  = xpb[(size_t)(g + u) * NXP + n];
      cC[u]  = xpb[(size_t)(g + u) * NXP + DSTATE + n];
    }
    float part[U];
    #pragma unroll
    for (int u = 0; u < U; ++u) {
      const float ab = __expf(cdt[u] * An);
      h = fmaf(ab, h, cdt[u] * cx[u] * cB[u]);
      part[u] = h * cC[u];
    }
    // Batched 16-lane reductions: 4 independent values per level -> ILP hides DS latency
    #pragma unroll
    for (int u = 0; u < U; ++u) part[u] += __shfl_xor(part[u], 1, 64);
    #pragma unroll
    for (int u = 0; u < U; ++u) part[u] += __shfl_xor(part[u], 2, 64);
    #pragma unroll
    for (int u = 0; u < U; ++u) part[u] += __shfl_xor(part[u], 4, 64);
    #pragma unroll
    for (int u = 0; u < U; ++u) part[u] += __shfl_xor(part[u], 8, 64);
    #pragma unroll
    for (int u = 0; u < U; ++u) {
      cum += cdt[u];
      if (n == 0) {
        const size_t base = cbase + (size_t)(g + u) * DI;
        y_local[base] = part[u];
        dtb[base] = cum;          // overwrite dt with inclusive cumsum
      }
    }
  }
  hloc[(((size_t)b * CHUNKS + c) * DI + d) * DSTATE + n] = h;
  if (n == 0) totdt[((size_t)b * CHUNKS + c) * DI + d] = cum;
}

// Pass 2: carry propagation across chunks. One thread per (b,d,n).
// hloc[c] becomes h_in[c] (state entering chunk c).
__global__ __launch_bounds__(256)
void scan_carry_kernel(float* __restrict__ hloc, const float* __restrict__ totdt,
                       const float* __restrict__ A_log) {
  const int tid = blockIdx.x * 256 + threadIdx.x;   // over NB*DI*DSTATE
  const int n = tid & 15;
  const int d = (tid >> 4) & (DI - 1);
  const int b = tid >> 15;
  const float An = -__expf(A_log[(size_t)d * DSTATE + n]);
  float h = 0.f;
  for (int c = 0; c < CHUNKS; ++c) {
    const size_t idx = (((size_t)b * CHUNKS + c) * DI + d) * DSTATE + n;
    const float le = hloc[idx];
    const float td = totdt[((size_t)b * CHUNKS + c) * DI + d];
    hloc[idx] = h;                       // h entering chunk c
    h = fmaf(__expf(An * td), h, le);    // h entering chunk c+1
  }
}

// Pass 3: fully-parallel correction + epilogue.
// y = (y_local + sum_n exp(An*cumdt)*h_in[n]*C_t[n] + x*D) * silu(z)
__global__ __launch_bounds__(256)
void scan_fix_kernel(const float* __restrict__ xc2, const float* __restrict__ dtb,
                     const float* __restrict__ xp, const float* __restrict__ zbuf,
                     const float* __restrict__ A_log, const float* __restrict__ Dp,
                     const float* __restrict__ hloc, float* __restrict__ y) {
  __shared__ float sA[256 * DSTATE];
  const int tid = threadIdx.x;
  const int idx = blockIdx.x * 256 + tid;
  const int d = idx & (DI - 1);
  const int l = (idx >> 11) & (LSEQ - 1);
  const int b = idx >> 22;
  const int d0 = (blockIdx.x & ((DI / 256) - 1)) * 256;   // block's d range start
  for (int i = tid; i < 256 * DSTATE; i += 256)
    sA[i] = -__expf(A_log[(size_t)d0 * DSTATE + i]);
  __syncthreads();

  const int c = l / LC;
  const float cum = dtb[idx];
  const float4* hin4 = (const float4*)&hloc[(((size_t)b * CHUNKS + c) * DI + d) * DSTATE];
  const float4* Ct4  = (const float4*)&xp[((size_t)b * LSEQ + l) * NXP + DTRANK + DSTATE];
  const float* Ar = &sA[(d - d0) * DSTATE];
  float corr = 0.f;
  #pragma unroll
  for (int q = 0; q < 4; ++q) {
    const float4 hv = hin4[q];
    const float4 cv = Ct4[q];
    corr = fmaf(__expf(Ar[4*q+0] * cum) * hv.x, cv.x, corr);
    corr = fmaf(__expf(Ar[4*q+1] * cum) * hv.y, cv.y, corr);
    corr = fmaf(__expf(Ar[4*q+2] * cum) * hv.z, cv.z, corr);
    corr = fmaf(__expf(Ar[4*q+3] * cum) * hv.w, cv.w, corr);
  }
  const float xv = xc2[idx], zv = zbuf[idx];
  y[idx] = (y[idx] + corr + xv * Dp[d]) * silu_f(zv);
}

extern "C" void kernel_launch(void* const* d_in, const int* in_sizes, int n_in,
                              void* d_out, int out_size, void* d_ws, size_t ws_size,
                              hipStream_t stream) {
  const float* x      = (const float*)d_in[0];
  const float* W_in   = (const float*)d_in[1];
  const float* conv_w = (const float*)d_in[2];
  const float* conv_b = (const float*)d_in[3];
  const float* W_xproj= (const float*)d_in[4];
  const float* W_dt   = (const float*)d_in[5];
  const float* b_dt   = (const float*)d_in[6];
  const float* A_log  = (const float*)d_in[7];
  const float* Dp     = (const float*)d_in[8];
  const float* W_out  = (const float*)d_in[9];
  float* out = (float*)d_out;
  float* ws  = (float*)d_ws;

  // ws layout (floats): xc_raw (reused as y) | z | xc2 | dt->cumdt | xp | hloc | totdt
  const size_t SEG = (size_t)NB * LSEQ * DI;     // 8,388,608
  float* xc_raw = ws;                 // pre-conv xc; later y_local / y
  float* zbuf   = ws + SEG;
  float* xc2    = ws + 2 * SEG;
  float* dtb    = ws + 3 * SEG;
  float* xp     = ws + 4 * SEG;                       // 4096*96 = 393216
  float* hloc   = xp + (size_t)MROWS * NXP;           // NB*CHUNKS*DI*16 = 524288
  float* totdt  = hloc + (size_t)NB * CHUNKS * DI * DSTATE;  // 32768

  dim3 blk(256);

  // GEMM1: xz = x @ W_in^T  -> xc_raw, zbuf
  gemm_nt<0><<<dim3(DI/128, MROWS/128), blk, 0, stream>>>(
      x, W_in,                     nullptr, xc_raw, DI, DMODEL, DMODEL, DMODEL, DI);
  gemm_nt<0><<<dim3(DI/128, MROWS/128), blk, 0, stream>>>(
      x, W_in + (size_t)DI*DMODEL, nullptr, zbuf,   DI, DMODEL, DMODEL, DMODEL, DI);

  // conv + bias + SiLU
  conv_silu_kernel<<<(NB*LSEQ*DI)/256, blk, 0, stream>>>(xc_raw, conv_w, conv_b, xc2);

  // GEMM2: xp = xc2 @ W_xproj^T  (N=96) — split-K=8, atomic accumulate
  hipMemsetAsync(xp, 0, (size_t)MROWS * NXP * sizeof(float), stream);
  gemm_nt_splitk<<<dim3(1, MROWS/128, 8), blk, 0, stream>>>(
      xc2, W_xproj, xp, NXP, DI, DI, NXP, DI/8);

  // GEMM3: dt = softplus(dt_lr @ W_dt^T + b_dt)
  gemm_nt<1><<<dim3(DI/128, MROWS/128), blk, 0, stream>>>(
      xp, W_dt, b_dt, dtb, DI, DTRANK, NXP, DTRANK, DI);

  // Chunked scan
  scan_chunk_kernel<<<dim3(DI/16, NB, CHUNKS), blk, 0, stream>>>(
      xc2, dtb, xp, A_log, xc_raw, hloc, totdt);
  scan_carry_kernel<<<(NB*DI*DSTATE)/256, blk, 0, stream>>>(hloc, totdt, A_log);
  scan_fix_kernel<<<(NB*LSEQ*DI)/256, blk, 0, stream>>>(
      xc2, dtb, xp, zbuf, A_log, Dp, hloc, xc_raw);

  // GEMM4: out = y @ W_out^T
  gemm_nt<0><<<dim3(DMODEL/128, MROWS/128), blk, 0, stream>>>(
      xc_raw, W_out, nullptr, out, DMODEL, DI, DI, DI, DMODEL);
}

// Round 5
// 734.020 us; speedup vs baseline: 3.1227x; 1.6552x over previous
//
#include <hip/hip_runtime.h>
#include <cstddef>
#include <cstdint>

// Problem constants (match reference)
#define DMODEL 1024
#define DI     2048      // D_INNER
#define LSEQ   2048
#define NB     2
#define DSTATE 16
#define DTRANK 64
#define NXP    96        // DT_RANK + 2*D_STATE
#define MROWS  (NB*LSEQ) // 4096 GEMM rows
#define CHUNKS 8
#define LC     (LSEQ/CHUNKS)   // 256

typedef __attribute__((ext_vector_type(8))) short bf16x8;
typedef __attribute__((ext_vector_type(4))) float f32x4;

__device__ __forceinline__ float silu_f(float v) {
  return v / (1.f + __expf(-v));
}
__device__ __forceinline__ float softplus_f(float v) {
  return (v > 20.f) ? v : log1pf(__expf(v));
}
__device__ __forceinline__ unsigned short f2bf(float f) {   // RNE
  unsigned u = __float_as_uint(f);
  unsigned r = (u + 0x7FFFu + ((u >> 16) & 1u)) >> 16;
  return (unsigned short)r;
}
__device__ __forceinline__ float bf2f(unsigned short h) {
  return __uint_as_float(((unsigned)h) << 16);
}
__device__ __forceinline__ void gl2lds16(const void* g, void* l) {
  __builtin_amdgcn_global_load_lds(
      (const __attribute__((address_space(1))) void*)g,
      (__attribute__((address_space(3))) void*)l, 16, 0, 0);
}

// fp32 -> (bf16 hi, bf16 lo), 4 elements/thread
__global__ __launch_bounds__(256)
void split_bf16_kernel(const float* __restrict__ in, unsigned short* __restrict__ hi,
                       unsigned short* __restrict__ lo, int n4) {
  int i = blockIdx.x * 256 + threadIdx.x;
  if (i >= n4) return;
  float4 v = ((const float4*)in)[i];
  ushort4 h, l;
  h.x = f2bf(v.x); h.y = f2bf(v.y); h.z = f2bf(v.z); h.w = f2bf(v.w);
  l.x = f2bf(v.x - bf2f(h.x)); l.y = f2bf(v.y - bf2f(h.y));
  l.z = f2bf(v.z - bf2f(h.z)); l.w = f2bf(v.w - bf2f(h.w));
  ((ushort4*)hi)[i] = h; ((ushort4*)lo)[i] = l;
}

// C[m,n] = sum_k A[m,k]*B[n,k] in bf16x3 (Ahi*Bhi + Ahi*Blo + Alo*Bhi).
// 128x128 tile, 256 threads (4 waves, 2x2 of 64x64), BK=64, 16x16x32 MFMA.
// global_load_lds (16B) staging with 16B-granule XOR swizzle (c ^= row&7) ->
// conflict-free ds_read_b128 fragment reads. M,N multiples of 128; K mult of 64.
__global__ __launch_bounds__(256)
void gemm_bf16x3(const unsigned short* __restrict__ Ahi, const unsigned short* __restrict__ Alo,
                 const unsigned short* __restrict__ Bhi, const unsigned short* __restrict__ Blo,
                 float* __restrict__ C, int N, int K) {
  __shared__ __align__(16) unsigned short Asl[128 * 64];   // 16 KB, swizzled granules
  __shared__ __align__(16) unsigned short Bsl[128 * 64];
  const int tid  = threadIdx.x;
  const int lane = tid & 63;
  const int wv   = tid >> 6;
  const int wm   = wv >> 1, wn = wv & 1;
  const int quad = lane >> 4, lr = lane & 15;
  const int bm = blockIdx.y * 128, bn = blockIdx.x * 128;

  // Staging decode (loop-invariant): slot s -> (row, granule c), c swizzled.
  int aOffE[4], bOffE[4], ldsOff[4];
  #pragma unroll
  for (int j = 0; j < 4; ++j) {
    const int s   = (wv * 4 + j) * 64 + lane;
    const int row = s >> 3;
    const int c   = (s & 7) ^ (row & 7);
    aOffE[j]  = (bm + row) * K + c * 8;
    bOffE[j]  = (bn + row) * K + c * 8;
    ldsOff[j] = (wv * 4 + j) << 10;   // bytes: 64 granules * 16B per instr
  }
  // Fragment read byte offsets (loop-invariant, swizzle-matched)
  int aRd[2][4], bRd[2][4];
  #pragma unroll
  for (int kk2 = 0; kk2 < 2; ++kk2)
    #pragma unroll
    for (int i = 0; i < 4; ++i) {
      const int ra = wm * 64 + i * 16 + lr;
      aRd[kk2][i] = ((ra << 3) + ((kk2 * 4 + quad) ^ (ra & 7))) << 4;
      const int rb = wn * 64 + i * 16 + lr;
      bRd[kk2][i] = ((rb << 3) + ((kk2 * 4 + quad) ^ (rb & 7))) << 4;
    }

  f32x4 acc[4][4];
  #pragma unroll
  for (int i = 0; i < 4; ++i)
    #pragma unroll
    for (int j = 0; j < 4; ++j)
      acc[i][j] = (f32x4){0.f, 0.f, 0.f, 0.f};

  const int K3 = 3 * K;
  for (int k0 = 0; k0 < K3; k0 += 64) {
    const unsigned short *Ap, *Bp;
    int km;
    if (k0 < K)            { Ap = Ahi; Bp = Bhi; km = k0; }
    else if (k0 < 2 * K)   { Ap = Ahi; Bp = Blo; km = k0 - K; }
    else                   { Ap = Alo; Bp = Bhi; km = k0 - 2 * K; }
    #pragma unroll
    for (int j = 0; j < 4; ++j) {
      gl2lds16(Ap + (size_t)aOffE[j] + km, (char*)Asl + ldsOff[j]);
      gl2lds16(Bp + (size_t)bOffE[j] + km, (char*)Bsl + ldsOff[j]);
    }
    __syncthreads();
    bf16x8 af[2][4], bfv[2][4];
    #pragma unroll
    for (int kk2 = 0; kk2 < 2; ++kk2)
      #pragma unroll
      for (int i = 0; i < 4; ++i) {
        af[kk2][i]  = *(const bf16x8*)((const char*)Asl + aRd[kk2][i]);
        bfv[kk2][i] = *(const bf16x8*)((const char*)Bsl + bRd[kk2][i]);
      }
    #pragma unroll
    for (int kk2 = 0; kk2 < 2; ++kk2)
      #pragma unroll
      for (int i = 0; i < 4; ++i)
        #pragma unroll
        for (int j = 0; j < 4; ++j)
          acc[i][j] = __builtin_amdgcn_mfma_f32_16x16x32_bf16(
              af[kk2][i], bfv[kk2][j], acc[i][j], 0, 0, 0);
    __syncthreads();
  }

  // Epilogue: C/D layout col=lane&15, row=quad*4+reg  [m89-verified]
  #pragma unroll
  for (int i = 0; i < 4; ++i) {
    const int gr = bm + wm * 64 + i * 16 + quad * 4;
    #pragma unroll
    for (int j = 0; j < 4; ++j) {
      const int gc = bn + wn * 64 + j * 16 + lr;
      float* cp = C + (size_t)gr * N + gc;
      #pragma unroll
      for (int r = 0; r < 4; ++r) cp[(size_t)r * N] = acc[i][j][r];
    }
  }
}

// fp32 GEMM kept for small shapes. C[m,n]=act(sum_k A[m,k]*B[n,k](+bias))
template<int ACT>
__global__ __launch_bounds__(256)
void gemm_nt(const float* __restrict__ A, const float* __restrict__ B,
             const float* __restrict__ bias, float* __restrict__ C,
             int N, int K, int lda, int ldb, int ldc) {
  __shared__ float As[16][132];
  __shared__ float Bs[16][132];
  const int tid = threadIdx.x;
  const int bm = blockIdx.y * 128, bn = blockIdx.x * 128;
  const int r  = tid >> 2;
  const int c4 = (tid & 3) << 2;
  const int ty = tid >> 4, tx = tid & 15;
  float acc[8][8];
  #pragma unroll
  for (int i = 0; i < 8; ++i)
    #pragma unroll
    for (int j = 0; j < 8; ++j) acc[i][j] = 0.f;

  for (int k0 = 0; k0 < K; k0 += 16) {
    float4 a0 = *(const float4*)(A + (size_t)(bm + r) * lda + k0 + c4);
    float4 a1 = *(const float4*)(A + (size_t)(bm + r + 64) * lda + k0 + c4);
    float4 b0 = make_float4(0.f, 0.f, 0.f, 0.f);
    float4 b1 = make_float4(0.f, 0.f, 0.f, 0.f);
    if (bn + r < N)      b0 = *(const float4*)(B + (size_t)(bn + r) * ldb + k0 + c4);
    if (bn + r + 64 < N) b1 = *(const float4*)(B + (size_t)(bn + r + 64) * ldb + k0 + c4);
    As[c4+0][r]    = a0.x; As[c4+1][r]    = a0.y; As[c4+2][r]    = a0.z; As[c4+3][r]    = a0.w;
    As[c4+0][r+64] = a1.x; As[c4+1][r+64] = a1.y; As[c4+2][r+64] = a1.z; As[c4+3][r+64] = a1.w;
    Bs[c4+0][r]    = b0.x; Bs[c4+1][r]    = b0.y; Bs[c4+2][r]    = b0.z; Bs[c4+3][r]    = b0.w;
    Bs[c4+0][r+64] = b1.x; Bs[c4+1][r+64] = b1.y; Bs[c4+2][r+64] = b1.z; Bs[c4+3][r+64] = b1.w;
    __syncthreads();
    #pragma unroll
    for (int k = 0; k < 16; ++k) {
      float4 av0 = *(const float4*)&As[k][ty*4];
      float4 av1 = *(const float4*)&As[k][64 + ty*4];
      float4 bv0 = *(const float4*)&Bs[k][tx*4];
      float4 bv1 = *(const float4*)&Bs[k][64 + tx*4];
      float a[8] = {av0.x, av0.y, av0.z, av0.w, av1.x, av1.y, av1.z, av1.w};
      float b[8] = {bv0.x, bv0.y, bv0.z, bv0.w, bv1.x, bv1.y, bv1.z, bv1.w};
      #pragma unroll
      for (int i = 0; i < 8; ++i)
        #pragma unroll
        for (int j = 0; j < 8; ++j)
          acc[i][j] = fmaf(a[i], b[j], acc[i][j]);
    }
    __syncthreads();
  }
  #pragma unroll
  for (int i = 0; i < 8; ++i) {
    const int m = bm + ty * 4 + (i & 3) + ((i >= 4) ? 64 : 0);
    #pragma unroll
    for (int j = 0; j < 8; ++j) {
      const int n = bn + tx * 4 + (j & 3) + ((j >= 4) ? 64 : 0);
      if (n < N) {
        float v = acc[i][j];
        if (ACT == 1) v = softplus_f(v + bias[n]);
        C[(size_t)m * ldc + n] = v;
      }
    }
  }
}

// Split-K fp32 GEMM, atomicAdd epilogue (C pre-zeroed).
__global__ __launch_bounds__(256)
void gemm_nt_splitk(const float* __restrict__ A, const float* __restrict__ B,
                    float* __restrict__ C,
                    int N, int lda, int ldb, int ldc, int kslice) {
  __shared__ float As[16][132];
  __shared__ float Bs[16][132];
  const int tid = threadIdx.x;
  const int bm = blockIdx.y * 128, bn = blockIdx.x * 128;
  const int kbeg = blockIdx.z * kslice, kend = kbeg + kslice;
  const int r  = tid >> 2;
  const int c4 = (tid & 3) << 2;
  const int ty = tid >> 4, tx = tid & 15;
  float acc[8][8];
  #pragma unroll
  for (int i = 0; i < 8; ++i)
    #pragma unroll
    for (int j = 0; j < 8; ++j) acc[i][j] = 0.f;

  for (int k0 = kbeg; k0 < kend; k0 += 16) {
    float4 a0 = *(const float4*)(A + (size_t)(bm + r) * lda + k0 + c4);
    float4 a1 = *(const float4*)(A + (size_t)(bm + r + 64) * lda + k0 + c4);
    float4 b0 = make_float4(0.f, 0.f, 0.f, 0.f);
    float4 b1 = make_float4(0.f, 0.f, 0.f, 0.f);
    if (bn + r < N)      b0 = *(const float4*)(B + (size_t)(bn + r) * ldb + k0 + c4);
    if (bn + r + 64 < N) b1 = *(const float4*)(B + (size_t)(bn + r + 64) * ldb + k0 + c4);
    As[c4+0][r]    = a0.x; As[c4+1][r]    = a0.y; As[c4+2][r]    = a0.z; As[c4+3][r]    = a0.w;
    As[c4+0][r+64] = a1.x; As[c4+1][r+64] = a1.y; As[c4+2][r+64] = a1.z; As[c4+3][r+64] = a1.w;
    Bs[c4+0][r]    = b0.x; Bs[c4+1][r]    = b0.y; Bs[c4+2][r]    = b0.z; Bs[c4+3][r]    = b0.w;
    Bs[c4+0][r+64] = b1.x; Bs[c4+1][r+64] = b1.y; Bs[c4+2][r+64] = b1.z; Bs[c4+3][r+64] = b1.w;
    __syncthreads();
    #pragma unroll
    for (int k = 0; k < 16; ++k) {
      float4 av0 = *(const float4*)&As[k][ty*4];
      float4 av1 = *(const float4*)&As[k][64 + ty*4];
      float4 bv0 = *(const float4*)&Bs[k][tx*4];
      float4 bv1 = *(const float4*)&Bs[k][64 + tx*4];
      float a[8] = {av0.x, av0.y, av0.z, av0.w, av1.x, av1.y, av1.z, av1.w};
      float b[8] = {bv0.x, bv0.y, bv0.z, bv0.w, bv1.x, bv1.y, bv1.z, bv1.w};
      #pragma unroll
      for (int i = 0; i < 8; ++i)
        #pragma unroll
        for (int j = 0; j < 8; ++j)
          acc[i][j] = fmaf(a[i], b[j], acc[i][j]);
    }
    __syncthreads();
  }
  #pragma unroll
  for (int i = 0; i < 8; ++i) {
    const int m = bm + ty * 4 + (i & 3) + ((i >= 4) ? 64 : 0);
    #pragma unroll
    for (int j = 0; j < 8; ++j) {
      const int n = bn + tx * 4 + (j & 3) + ((j >= 4) ? 64 : 0);
      if (n < N) atomicAdd(&C[(size_t)m * ldc + n], acc[i][j]);
    }
  }
}

// Causal depthwise conv (width 4) + bias + SiLU.  xc2[b,l,d]
__global__ __launch_bounds__(256)
void conv_silu_kernel(const float* __restrict__ xc_raw, const float* __restrict__ cw,
                      const float* __restrict__ cb, float* __restrict__ xc2) {
  const int idx = blockIdx.x * 256 + threadIdx.x;
  const int d = idx & (DI - 1);
  const int l = (idx >> 11) & (LSEQ - 1);
  const int b = idx >> 22;
  float acc = cb[d];
  #pragma unroll
  for (int j = 0; j < 4; ++j) {
    const int ls = l - 3 + j;
    if (ls >= 0)
      acc = fmaf(xc_raw[((size_t)b * LSEQ + ls) * DI + d], cw[d * 4 + j], acc);
  }
  xc2[idx] = silu_f(acc);
}

// ---- Chunked selective scan ----
__global__ __launch_bounds__(256, 8)
void scan_chunk_kernel(const float* __restrict__ xc2, float* __restrict__ dtb,
                       const float* __restrict__ xp, const float* __restrict__ A_log,
                       float* __restrict__ y_local, float* __restrict__ hloc,
                       float* __restrict__ totdt) {
  const int b    = blockIdx.y;
  const int c    = blockIdx.z;
  const int lane = threadIdx.x & 63;
  const int wv   = threadIdx.x >> 6;
  const int n    = lane & 15;
  const int dl   = lane >> 4;
  const int d    = blockIdx.x * 16 + wv * 4 + dl;

  const float An = -__expf(A_log[(size_t)d * DSTATE + n]);
  float h = 0.f, cum = 0.f;
  const int t0c = c * LC;
  const float* xpb = xp + ((size_t)b * LSEQ + t0c) * NXP + DTRANK;
  const size_t cbase = ((size_t)b * LSEQ + t0c) * DI + d;

  constexpr int U = 4;
  for (int g = 0; g < LC; g += U) {
    float cdt[U], cx[U], cB[U], cC[U];
    #pragma unroll
    for (int u = 0; u < U; ++u) {
      const size_t base = cbase + (size_t)(g + u) * DI;
      cdt[u] = dtb[base];
      cx[u]  = xc2[base];
      cB[u]  = xpb[(size_t)(g + u) * NXP + n];
      cC[u]  = xpb[(size_t)(g + u) * NXP + DSTATE + n];
    }
    float part[U];
    #pragma unroll
    for (int u = 0; u < U; ++u) {
      const float ab = __expf(cdt[u] * An);
      h = fmaf(ab, h, cdt[u] * cx[u] * cB[u]);
      part[u] = h * cC[u];
    }
    #pragma unroll
    for (int u = 0; u < U; ++u) part[u] += __shfl_xor(part[u], 1, 64);
    #pragma unroll
    for (int u = 0; u < U; ++u) part[u] += __shfl_xor(part[u], 2, 64);
    #pragma unroll
    for (int u = 0; u < U; ++u) part[u] += __shfl_xor(part[u], 4, 64);
    #pragma unroll
    for (int u = 0; u < U; ++u) part[u] += __shfl_xor(part[u], 8, 64);
    #pragma unroll
    for (int u = 0; u < U; ++u) {
      cum += cdt[u];
      if (n == 0) {
        const size_t base = cbase + (size_t)(g + u) * DI;
        y_local[base] = part[u];
        dtb[base] = cum;
      }
    }
  }
  hloc[(((size_t)b * CHUNKS + c) * DI + d) * DSTATE + n] = h;
  if (n == 0) totdt[((size_t)b * CHUNKS + c) * DI + d] = cum;
}

__global__ __launch_bounds__(256)
void scan_carry_kernel(float* __restrict__ hloc, const float* __restrict__ totdt,
                       const float* __restrict__ A_log) {
  const int tid = blockIdx.x * 256 + threadIdx.x;
  const int n = tid & 15;
  const int d = (tid >> 4) & (DI - 1);
  const int b = tid >> 15;
  const float An = -__expf(A_log[(size_t)d * DSTATE + n]);
  float h = 0.f;
  for (int c = 0; c < CHUNKS; ++c) {
    const size_t idx = (((size_t)b * CHUNKS + c) * DI + d) * DSTATE + n;
    const float le = hloc[idx];
    const float td = totdt[((size_t)b * CHUNKS + c) * DI + d];
    hloc[idx] = h;
    h = fmaf(__expf(An * td), h, le);
  }
}

// Correction + epilogue.
__global__ __launch_bounds__(256)
void scan_fix_kernel(const float* __restrict__ xc2, const float* __restrict__ dtb,
                     const float* __restrict__ xp, const float* __restrict__ zbuf,
                     const float* __restrict__ A_log, const float* __restrict__ Dp,
                     const float* __restrict__ hloc, float* __restrict__ y) {
  __shared__ float sA[256 * DSTATE];
  const int tid = threadIdx.x;
  const int idx = blockIdx.x * 256 + tid;
  const int d = idx & (DI - 1);
  const int l = (idx >> 11) & (LSEQ - 1);
  const int b = idx >> 22;
  const int d0 = (blockIdx.x & ((DI / 256) - 1)) * 256;
  for (int i = tid; i < 256 * DSTATE; i += 256)
    sA[i] = -__expf(A_log[(size_t)d0 * DSTATE + i]);
  __syncthreads();

  const int c = l / LC;
  const float cum = dtb[idx];
  const float4* hin4 = (const float4*)&hloc[(((size_t)b * CHUNKS + c) * DI + d) * DSTATE];
  const float4* Ct4  = (const float4*)&xp[((size_t)b * LSEQ + l) * NXP + DTRANK + DSTATE];
  const float* Ar = &sA[(d - d0) * DSTATE];
  float corr = 0.f;
  #pragma unroll
  for (int q = 0; q < 4; ++q) {
    const float4 hv = hin4[q];
    const float4 cv = Ct4[q];
    corr = fmaf(__expf(Ar[4*q+0] * cum) * hv.x, cv.x, corr);
    corr = fmaf(__expf(Ar[4*q+1] * cum) * hv.y, cv.y, corr);
    corr = fmaf(__expf(Ar[4*q+2] * cum) * hv.z, cv.z, corr);
    corr = fmaf(__expf(Ar[4*q+3] * cum) * hv.w, cv.w, corr);
  }
  const float xv = xc2[idx], zv = zbuf[idx];
  y[idx] = (y[idx] + corr + xv * Dp[d]) * silu_f(zv);
}

extern "C" void kernel_launch(void* const* d_in, const int* in_sizes, int n_in,
                              void* d_out, int out_size, void* d_ws, size_t ws_size,
                              hipStream_t stream) {
  const float* x      = (const float*)d_in[0];
  const float* W_in   = (const float*)d_in[1];
  const float* conv_w = (const float*)d_in[2];
  const float* conv_b = (const float*)d_in[3];
  const float* W_xproj= (const float*)d_in[4];
  const float* W_dt   = (const float*)d_in[5];
  const float* b_dt   = (const float*)d_in[6];
  const float* A_log  = (const float*)d_in[7];
  const float* Dp     = (const float*)d_in[8];
  const float* W_out  = (const float*)d_in[9];
  float* out = (float*)d_out;
  float* ws  = (float*)d_ws;

  // ws layout (floats), 138 MB total — identical footprint to the proven round-3 layout:
  //   xc_raw[SEG] | zbuf[SEG] | xc2[SEG] | dtb[SEG] | xp | hloc | totdt
  // Overlays (time-disjoint):
  //   stage-1 bf16 pool (xhi,xlo,Whi,Wlo = exactly SEG floats) over dtb
  //     (dtb first written by GEMM3, after GEMM1a/b consumed the pool).
  //   stage-4 bf16 pool (yhi,ylo,Wohi,Wolo = 10.5M floats) over zbuf+xc2
  //     (both dead after scan_fix).
  //   y reuses xc_raw (dead after conv).
  const size_t SEG = (size_t)NB * LSEQ * DI;            // 8,388,608
  float* xc_raw = ws;                                   // later y_local / y
  float* zbuf   = ws + SEG;
  float* xc2    = ws + 2 * SEG;
  float* dtb    = ws + 3 * SEG;
  float* xp     = ws + 4 * SEG;                         // 393,216
  float* hloc   = xp + (size_t)MROWS * NXP;             // 524,288
  float* totdt  = hloc + (size_t)NB * CHUNKS * DI * DSTATE;  // 32,768

  unsigned short* xhi = (unsigned short*)dtb;           // 4,194,304 bf16
  unsigned short* xlo = xhi + (size_t)MROWS * DMODEL;   // 4,194,304 bf16
  unsigned short* Whi = xlo + (size_t)MROWS * DMODEL;   // 4,194,304 bf16 (full 2*DI x DMODEL)
  unsigned short* Wlo = Whi + (size_t)2 * DI * DMODEL;  // FIXED: full size, no overlap

  unsigned short* yhi  = (unsigned short*)zbuf;         // SEG bf16
  unsigned short* ylo  = yhi + SEG;                     // SEG bf16 (spills into xc2 region: dead)
  unsigned short* Wohi = ylo + SEG;
  unsigned short* Wolo = Wohi + (size_t)DMODEL * DI;

  float* yb = xc_raw;
  dim3 blk(256);

  // Convert x and W_in to bf16 hi/lo
  split_bf16_kernel<<<(MROWS*DMODEL/4 + 255)/256, blk, 0, stream>>>(x, xhi, xlo, MROWS*DMODEL/4);
  split_bf16_kernel<<<(2*DI*DMODEL/4 + 255)/256, blk, 0, stream>>>(W_in, Whi, Wlo, 2*DI*DMODEL/4);

  // GEMM1a: xc = x @ W_in[0:2048]^T   (M=4096, N=2048, K=1024)
  gemm_bf16x3<<<dim3(DI/128, MROWS/128), blk, 0, stream>>>(
      xhi, xlo, Whi, Wlo, xc_raw, DI, DMODEL);
  // GEMM1b: z = x @ W_in[2048:4096]^T
  gemm_bf16x3<<<dim3(DI/128, MROWS/128), blk, 0, stream>>>(
      xhi, xlo, Whi + (size_t)DI*DMODEL, Wlo + (size_t)DI*DMODEL, zbuf, DI, DMODEL);

  // conv + bias + SiLU
  conv_silu_kernel<<<(NB*LSEQ*DI)/256, blk, 0, stream>>>(xc_raw, conv_w, conv_b, xc2);

  // GEMM2: xp = xc2 @ W_xproj^T  (N=96) — split-K=8 fp32, atomic accumulate
  hipMemsetAsync(xp, 0, (size_t)MROWS * NXP * sizeof(float), stream);
  gemm_nt_splitk<<<dim3(1, MROWS/128, 8), blk, 0, stream>>>(
      xc2, W_xproj, xp, NXP, DI, DI, NXP, DI/8);

  // GEMM3: dt = softplus(dt_lr @ W_dt^T + b_dt)  (fp32, K=64; dtb overlay now dead)
  gemm_nt<1><<<dim3(DI/128, MROWS/128), blk, 0, stream>>>(
      xp, W_dt, b_dt, dtb, DI, DTRANK, NXP, DTRANK, DI);

  // Chunked scan -> yb (= xc_raw, dead after conv)
  scan_chunk_kernel<<<dim3(DI/16, NB, CHUNKS), blk, 0, stream>>>(
      xc2, dtb, xp, A_log, yb, hloc, totdt);
  scan_carry_kernel<<<(NB*DI*DSTATE)/256, blk, 0, stream>>>(hloc, totdt, A_log);
  scan_fix_kernel<<<(NB*LSEQ*DI)/256, blk, 0, stream>>>(
      xc2, dtb, xp, zbuf, A_log, Dp, hloc, yb);

  // Convert y and W_out (zbuf/xc2 dead now); GEMM4: out = y @ W_out^T
  split_bf16_kernel<<<(NB*LSEQ*DI/4 + 255)/256, blk, 0, stream>>>(yb, yhi, ylo, NB*LSEQ*DI/4);
  split_bf16_kernel<<<(DMODEL*DI/4 + 255)/256, blk, 0, stream>>>(W_out, Wohi, Wolo, DMODEL*DI/4);
  gemm_bf16x3<<<dim3(DMODEL/128, MROWS/128), blk, 0, stream>>>(
      yhi, ylo, Wohi, Wolo, out, DMODEL, DI);
}

// Round 6
// 732.021 us; speedup vs baseline: 3.1313x; 1.0027x over previous
//
#include <hip/hip_runtime.h>
#include <cstddef>
#include <cstdint>

// Problem constants (match reference)
#define DMODEL 1024
#define DI     2048      // D_INNER
#define LSEQ   2048
#define NB     2
#define DSTATE 16
#define DTRANK 64
#define NXP    96        // DT_RANK + 2*D_STATE
#define MROWS  (NB*LSEQ) // 4096 GEMM rows
#define CHUNKS 8
#define LC     (LSEQ/CHUNKS)   // 256

typedef __attribute__((ext_vector_type(8))) short bf16x8;
typedef __attribute__((ext_vector_type(4))) float f32x4;

__device__ __forceinline__ float silu_f(float v) {
  return v / (1.f + __expf(-v));
}
__device__ __forceinline__ float softplus_f(float v) {
  return (v > 20.f) ? v : log1pf(__expf(v));
}
__device__ __forceinline__ unsigned short f2bf(float f) {   // RNE
  unsigned u = __float_as_uint(f);
  unsigned r = (u + 0x7FFFu + ((u >> 16) & 1u)) >> 16;
  return (unsigned short)r;
}
__device__ __forceinline__ float bf2f(unsigned short h) {
  return __uint_as_float(((unsigned)h) << 16);
}
__device__ __forceinline__ void gl2lds16(const void* g, void* l) {
  __builtin_amdgcn_global_load_lds(
      (const __attribute__((address_space(1))) void*)g,
      (__attribute__((address_space(3))) void*)l, 16, 0, 0);
}

// fp32 -> (bf16 hi, bf16 lo), 4 elements/thread
__global__ __launch_bounds__(256)
void split_bf16_kernel(const float* __restrict__ in, unsigned short* __restrict__ hi,
                       unsigned short* __restrict__ lo, int n4) {
  int i = blockIdx.x * 256 + threadIdx.x;
  if (i >= n4) return;
  float4 v = ((const float4*)in)[i];
  ushort4 h, l;
  h.x = f2bf(v.x); h.y = f2bf(v.y); h.z = f2bf(v.z); h.w = f2bf(v.w);
  l.x = f2bf(v.x - bf2f(h.x)); l.y = f2bf(v.y - bf2f(h.y));
  l.z = f2bf(v.z - bf2f(h.z)); l.w = f2bf(v.w - bf2f(h.w));
  ((ushort4*)hi)[i] = h; ((ushort4*)lo)[i] = l;
}

// C[m,n] = sum_k A[m,k]*B[n,k] in bf16x3 (Ahi*Bhi + Ahi*Blo + Alo*Bhi).
// 128x128 tile, 256 threads (4 waves, 2x2 of 64x64), BK=64, 16x16x32 MFMA.
// global_load_lds (16B) staging with 16B-granule XOR swizzle -> conflict-free
// ds_read_b128 fragment reads.
// Dual-output: block cols [0,NC) -> C0, [NC,2NC) -> C1 (ld = NC). Split-K via
// blockIdx.z (klen per slice); ATOMIC=true accumulates with atomicAdd.
template<bool ATOMIC>
__global__ __launch_bounds__(256)
void gemm_bf16x3(const unsigned short* __restrict__ Ahi, const unsigned short* __restrict__ Alo,
                 const unsigned short* __restrict__ Bhi, const unsigned short* __restrict__ Blo,
                 float* __restrict__ C0, float* __restrict__ C1,
                 int NC, int K, int klen) {
  __shared__ __align__(16) unsigned short Asl[128 * 64];   // 16 KB, swizzled granules
  __shared__ __align__(16) unsigned short Bsl[128 * 64];
  const int tid  = threadIdx.x;
  const int lane = tid & 63;
  const int wv   = tid >> 6;
  const int wm   = wv >> 1, wn = wv & 1;
  const int quad = lane >> 4, lr = lane & 15;
  const int bm = blockIdx.y * 128, bn = blockIdx.x * 128;
  const int kbeg = blockIdx.z * klen, kend = kbeg + klen;

  // Staging decode (loop-invariant): slot s -> (row, granule c), c swizzled.
  int aOffE[4], bOffE[4], ldsOff[4];
  #pragma unroll
  for (int j = 0; j < 4; ++j) {
    const int s   = (wv * 4 + j) * 64 + lane;
    const int row = s >> 3;
    const int c   = (s & 7) ^ (row & 7);
    aOffE[j]  = (bm + row) * K + c * 8;
    bOffE[j]  = (bn + row) * K + c * 8;
    ldsOff[j] = (wv * 4 + j) << 10;   // bytes: 64 granules * 16B per instr
  }
  // Fragment read byte offsets (loop-invariant, swizzle-matched)
  int aRd[2][4], bRd[2][4];
  #pragma unroll
  for (int kk2 = 0; kk2 < 2; ++kk2)
    #pragma unroll
    for (int i = 0; i < 4; ++i) {
      const int ra = wm * 64 + i * 16 + lr;
      aRd[kk2][i] = ((ra << 3) + ((kk2 * 4 + quad) ^ (ra & 7))) << 4;
      const int rb = wn * 64 + i * 16 + lr;
      bRd[kk2][i] = ((rb << 3) + ((kk2 * 4 + quad) ^ (rb & 7))) << 4;
    }

  f32x4 acc[4][4];
  #pragma unroll
  for (int i = 0; i < 4; ++i)
    #pragma unroll
    for (int j = 0; j < 4; ++j)
      acc[i][j] = (f32x4){0.f, 0.f, 0.f, 0.f};

  #pragma unroll 1
  for (int ph = 0; ph < 3; ++ph) {
    const unsigned short* Ap = (ph == 2) ? Alo : Ahi;
    const unsigned short* Bp = (ph == 1) ? Blo : Bhi;
    #pragma unroll 1
    for (int km = kbeg; km < kend; km += 64) {
      #pragma unroll
      for (int j = 0; j < 4; ++j) {
        gl2lds16(Ap + (size_t)aOffE[j] + km, (char*)Asl + ldsOff[j]);
        gl2lds16(Bp + (size_t)bOffE[j] + km, (char*)Bsl + ldsOff[j]);
      }
      __syncthreads();
      bf16x8 af[2][4], bfv[2][4];
      #pragma unroll
      for (int kk2 = 0; kk2 < 2; ++kk2)
        #pragma unroll
        for (int i = 0; i < 4; ++i) {
          af[kk2][i]  = *(const bf16x8*)((const char*)Asl + aRd[kk2][i]);
          bfv[kk2][i] = *(const bf16x8*)((const char*)Bsl + bRd[kk2][i]);
        }
      #pragma unroll
      for (int kk2 = 0; kk2 < 2; ++kk2)
        #pragma unroll
        for (int i = 0; i < 4; ++i)
          #pragma unroll
          for (int j = 0; j < 4; ++j)
            acc[i][j] = __builtin_amdgcn_mfma_f32_16x16x32_bf16(
                af[kk2][i], bfv[kk2][j], acc[i][j], 0, 0, 0);
      __syncthreads();
    }
  }

  // Output select (wave-uniform per block): cols [0,NC)->C0, [NC,2NC)->C1
  float* C = C0;
  int bnc = bn;
  if (bn >= NC) { C = C1; bnc = bn - NC; }

  // Epilogue: C/D layout col=lane&15, row=quad*4+reg  [m89-verified]
  #pragma unroll
  for (int i = 0; i < 4; ++i) {
    const int gr = bm + wm * 64 + i * 16 + quad * 4;
    #pragma unroll
    for (int j = 0; j < 4; ++j) {
      const int gc = bnc + wn * 64 + j * 16 + lr;
      float* cp = C + (size_t)gr * NC + gc;
      #pragma unroll
      for (int r = 0; r < 4; ++r) {
        if (ATOMIC) atomicAdd(&cp[(size_t)r * NC], acc[i][j][r]);
        else        cp[(size_t)r * NC] = acc[i][j][r];
      }
    }
  }
}

// fp32 GEMM kept for small shapes. C[m,n]=act(sum_k A[m,k]*B[n,k](+bias))
template<int ACT>
__global__ __launch_bounds__(256)
void gemm_nt(const float* __restrict__ A, const float* __restrict__ B,
             const float* __restrict__ bias, float* __restrict__ C,
             int N, int K, int lda, int ldb, int ldc) {
  __shared__ float As[16][132];
  __shared__ float Bs[16][132];
  const int tid = threadIdx.x;
  const int bm = blockIdx.y * 128, bn = blockIdx.x * 128;
  const int r  = tid >> 2;
  const int c4 = (tid & 3) << 2;
  const int ty = tid >> 4, tx = tid & 15;
  float acc[8][8];
  #pragma unroll
  for (int i = 0; i < 8; ++i)
    #pragma unroll
    for (int j = 0; j < 8; ++j) acc[i][j] = 0.f;

  for (int k0 = 0; k0 < K; k0 += 16) {
    float4 a0 = *(const float4*)(A + (size_t)(bm + r) * lda + k0 + c4);
    float4 a1 = *(const float4*)(A + (size_t)(bm + r + 64) * lda + k0 + c4);
    float4 b0 = make_float4(0.f, 0.f, 0.f, 0.f);
    float4 b1 = make_float4(0.f, 0.f, 0.f, 0.f);
    if (bn + r < N)      b0 = *(const float4*)(B + (size_t)(bn + r) * ldb + k0 + c4);
    if (bn + r + 64 < N) b1 = *(const float4*)(B + (size_t)(bn + r + 64) * ldb + k0 + c4);
    As[c4+0][r]    = a0.x; As[c4+1][r]    = a0.y; As[c4+2][r]    = a0.z; As[c4+3][r]    = a0.w;
    As[c4+0][r+64] = a1.x; As[c4+1][r+64] = a1.y; As[c4+2][r+64] = a1.z; As[c4+3][r+64] = a1.w;
    Bs[c4+0][r]    = b0.x; Bs[c4+1][r]    = b0.y; Bs[c4+2][r]    = b0.z; Bs[c4+3][r]    = b0.w;
    Bs[c4+0][r+64] = b1.x; Bs[c4+1][r+64] = b1.y; Bs[c4+2][r+64] = b1.z; Bs[c4+3][r+64] = b1.w;
    __syncthreads();
    #pragma unroll
    for (int k = 0; k < 16; ++k) {
      float4 av0 = *(const float4*)&As[k][ty*4];
      float4 av1 = *(const float4*)&As[k][64 + ty*4];
      float4 bv0 = *(const float4*)&Bs[k][tx*4];
      float4 bv1 = *(const float4*)&Bs[k][64 + tx*4];
      float a[8] = {av0.x, av0.y, av0.z, av0.w, av1.x, av1.y, av1.z, av1.w};
      float b[8] = {bv0.x, bv0.y, bv0.z, bv0.w, bv1.x, bv1.y, bv1.z, bv1.w};
      #pragma unroll
      for (int i = 0; i < 8; ++i)
        #pragma unroll
        for (int j = 0; j < 8; ++j)
          acc[i][j] = fmaf(a[i], b[j], acc[i][j]);
    }
    __syncthreads();
  }
  #pragma unroll
  for (int i = 0; i < 8; ++i) {
    const int m = bm + ty * 4 + (i & 3) + ((i >= 4) ? 64 : 0);
    #pragma unroll
    for (int j = 0; j < 8; ++j) {
      const int n = bn + tx * 4 + (j & 3) + ((j >= 4) ? 64 : 0);
      if (n < N) {
        float v = acc[i][j];
        if (ACT == 1) v = softplus_f(v + bias[n]);
        C[(size_t)m * ldc + n] = v;
      }
    }
  }
}

// Split-K fp32 GEMM, atomicAdd epilogue (C pre-zeroed).
__global__ __launch_bounds__(256)
void gemm_nt_splitk(const float* __restrict__ A, const float* __restrict__ B,
                    float* __restrict__ C,
                    int N, int lda, int ldb, int ldc, int kslice) {
  __shared__ float As[16][132];
  __shared__ float Bs[16][132];
  const int tid = threadIdx.x;
  const int bm = blockIdx.y * 128, bn = blockIdx.x * 128;
  const int kbeg = blockIdx.z * kslice, kend = kbeg + kslice;
  const int r  = tid >> 2;
  const int c4 = (tid & 3) << 2;
  const int ty = tid >> 4, tx = tid & 15;
  float acc[8][8];
  #pragma unroll
  for (int i = 0; i < 8; ++i)
    #pragma unroll
    for (int j = 0; j < 8; ++j) acc[i][j] = 0.f;

  for (int k0 = kbeg; k0 < kend; k0 += 16) {
    float4 a0 = *(const float4*)(A + (size_t)(bm + r) * lda + k0 + c4);
    float4 a1 = *(const float4*)(A + (size_t)(bm + r + 64) * lda + k0 + c4);
    float4 b0 = make_float4(0.f, 0.f, 0.f, 0.f);
    float4 b1 = make_float4(0.f, 0.f, 0.f, 0.f);
    if (bn + r < N)      b0 = *(const float4*)(B + (size_t)(bn + r) * ldb + k0 + c4);
    if (bn + r + 64 < N) b1 = *(const float4*)(B + (size_t)(bn + r + 64) * ldb + k0 + c4);
    As[c4+0][r]    = a0.x; As[c4+1][r]    = a0.y; As[c4+2][r]    = a0.z; As[c4+3][r]    = a0.w;
    As[c4+0][r+64] = a1.x; As[c4+1][r+64] = a1.y; As[c4+2][r+64] = a1.z; As[c4+3][r+64] = a1.w;
    Bs[c4+0][r]    = b0.x; Bs[c4+1][r]    = b0.y; Bs[c4+2][r]    = b0.z; Bs[c4+3][r]    = b0.w;
    Bs[c4+0][r+64] = b1.x; Bs[c4+1][r+64] = b1.y; Bs[c4+2][r+64] = b1.z; Bs[c4+3][r+64] = b1.w;
    __syncthreads();
    #pragma unroll
    for (int k = 0; k < 16; ++k) {
      float4 av0 = *(const float4*)&As[k][ty*4];
      float4 av1 = *(const float4*)&As[k][64 + ty*4];
      float4 bv0 = *(const float4*)&Bs[k][tx*4];
      float4 bv1 = *(const float4*)&Bs[k][64 + tx*4];
      float a[8] = {av0.x, av0.y, av0.z, av0.w, av1.x, av1.y, av1.z, av1.w};
      float b[8] = {bv0.x, bv0.y, bv0.z, bv0.w, bv1.x, bv1.y, bv1.z, bv1.w};
      #pragma unroll
      for (int i = 0; i < 8; ++i)
        #pragma unroll
        for (int j = 0; j < 8; ++j)
          acc[i][j] = fmaf(a[i], b[j], acc[i][j]);
    }
    __syncthreads();
  }
  #pragma unroll
  for (int i = 0; i < 8; ++i) {
    const int m = bm + ty * 4 + (i & 3) + ((i >= 4) ? 64 : 0);
    #pragma unroll
    for (int j = 0; j < 8; ++j) {
      const int n = bn + tx * 4 + (j & 3) + ((j >= 4) ? 64 : 0);
      if (n < N) atomicAdd(&C[(size_t)m * ldc + n], acc[i][j]);
    }
  }
}

// Causal depthwise conv (width 4) + bias + SiLU.  xc2[b,l,d]
__global__ __launch_bounds__(256)
void conv_silu_kernel(const float* __restrict__ xc_raw, const float* __restrict__ cw,
                      const float* __restrict__ cb, float* __restrict__ xc2) {
  const int idx = blockIdx.x * 256 + threadIdx.x;
  const int d = idx & (DI - 1);
  const int l = (idx >> 11) & (LSEQ - 1);
  const int b = idx >> 22;
  float acc = cb[d];
  #pragma unroll
  for (int j = 0; j < 4; ++j) {
    const int ls = l - 3 + j;
    if (ls >= 0)
      acc = fmaf(xc_raw[((size_t)b * LSEQ + ls) * DI + d], cw[d * 4 + j], acc);
  }
  xc2[idx] = silu_f(acc);
}

// ---- Chunked selective scan ----
// Pass 1: per-chunk local scan, 16 lanes per (b,d) channel (one per state).
// B/C staged in LDS per 128-step half-chunk (shared by all 16 channels of the
// block): 2 ds_read_b32 replace 2 strided global loads per timestep.
__global__ __launch_bounds__(256, 8)
void scan_chunk_kernel(const float* __restrict__ xc2, float* __restrict__ dtb,
                       const float* __restrict__ xp, const float* __restrict__ A_log,
                       float* __restrict__ y_local, float* __restrict__ hloc,
                       float* __restrict__ totdt) {
  __shared__ float sbc[128][32];   // [t-in-half][0:16)=B, [16:32)=C  (16 KB)
  const int b    = blockIdx.y;
  const int c    = blockIdx.z;
  const int lane = threadIdx.x & 63;
  const int wv   = threadIdx.x >> 6;
  const int n    = lane & 15;
  const int dl   = lane >> 4;
  const int d    = blockIdx.x * 16 + wv * 4 + dl;

  const float An = -__expf(A_log[(size_t)d * DSTATE + n]);
  float h = 0.f, cum = 0.f;
  const int t0c = c * LC;
  const float* xpb = xp + ((size_t)b * LSEQ + t0c) * NXP + DTRANK;  // B/C block of row
  const size_t cbase = ((size_t)b * LSEQ + t0c) * DI + d;

  constexpr int U = 8;
  #pragma unroll 1
  for (int half = 0; half < 2; ++half) {
    const int tH = half * 128;
    __syncthreads();
    #pragma unroll
    for (int kk = 0; kk < 4; ++kk) {
      const int slot = threadIdx.x + kk * 256;          // 0..1023 float4 slots
      const int row  = slot >> 3, c4 = (slot & 7) << 2;
      *(float4*)&sbc[row][c4] = *(const float4*)&xpb[(size_t)(tH + row) * NXP + c4];
    }
    __syncthreads();
    #pragma unroll 1
    for (int g = 0; g < 128; g += U) {
      float cdt[U], cx[U], cB[U], cC[U];
      #pragma unroll
      for (int u = 0; u < U; ++u) {
        const size_t base = cbase + (size_t)(tH + g + u) * DI;
        cdt[u] = dtb[base];
        cx[u]  = xc2[base];
      }
      #pragma unroll
      for (int u = 0; u < U; ++u) {
        cB[u] = sbc[g + u][n];
        cC[u] = sbc[g + u][16 + n];
      }
      float part[U];
      #pragma unroll
      for (int u = 0; u < U; ++u) {
        const float ab = __expf(cdt[u] * An);
        h = fmaf(ab, h, cdt[u] * cx[u] * cB[u]);
        part[u] = h * cC[u];
      }
      #pragma unroll
      for (int u = 0; u < U; ++u) part[u] += __shfl_xor(part[u], 1, 64);
      #pragma unroll
      for (int u = 0; u < U; ++u) part[u] += __shfl_xor(part[u], 2, 64);
      #pragma unroll
      for (int u = 0; u < U; ++u) part[u] += __shfl_xor(part[u], 4, 64);
      #pragma unroll
      for (int u = 0; u < U; ++u) part[u] += __shfl_xor(part[u], 8, 64);
      #pragma unroll
      for (int u = 0; u < U; ++u) {
        cum += cdt[u];
        if (n == 0) {
          const size_t base = cbase + (size_t)(tH + g + u) * DI;
          y_local[base] = part[u];
          dtb[base] = cum;          // overwrite dt with inclusive cumsum
        }
      }
    }
  }
  hloc[(((size_t)b * CHUNKS + c) * DI + d) * DSTATE + n] = h;
  if (n == 0) totdt[((size_t)b * CHUNKS + c) * DI + d] = cum;
}

__global__ __launch_bounds__(256)
void scan_carry_kernel(float* __restrict__ hloc, const float* __restrict__ totdt,
                       const float* __restrict__ A_log) {
  const int tid = blockIdx.x * 256 + threadIdx.x;
  const int n = tid & 15;
  const int d = (tid >> 4) & (DI - 1);
  const int b = tid >> 15;
  const float An = -__expf(A_log[(size_t)d * DSTATE + n]);
  float h = 0.f;
  for (int c = 0; c < CHUNKS; ++c) {
    const size_t idx = (((size_t)b * CHUNKS + c) * DI + d) * DSTATE + n;
    const float le = hloc[idx];
    const float td = totdt[((size_t)b * CHUNKS + c) * DI + d];
    hloc[idx] = h;
    h = fmaf(__expf(An * td), h, le);
  }
}

// Correction + epilogue.
__global__ __launch_bounds__(256)
void scan_fix_kernel(const float* __restrict__ xc2, const float* __restrict__ dtb,
                     const float* __restrict__ xp, const float* __restrict__ zbuf,
                     const float* __restrict__ A_log, const float* __restrict__ Dp,
                     const float* __restrict__ hloc, float* __restrict__ y) {
  __shared__ float sA[256 * DSTATE];
  const int tid = threadIdx.x;
  const int idx = blockIdx.x * 256 + tid;
  const int d = idx & (DI - 1);
  const int l = (idx >> 11) & (LSEQ - 1);
  const int b = idx >> 22;
  const int d0 = (blockIdx.x & ((DI / 256) - 1)) * 256;
  for (int i = tid; i < 256 * DSTATE; i += 256)
    sA[i] = -__expf(A_log[(size_t)d0 * DSTATE + i]);
  __syncthreads();

  const int c = l / LC;
  const float cum = dtb[idx];
  const float4* hin4 = (const float4*)&hloc[(((size_t)b * CHUNKS + c) * DI + d) * DSTATE];
  const float4* Ct4  = (const float4*)&xp[((size_t)b * LSEQ + l) * NXP + DTRANK + DSTATE];
  const float* Ar = &sA[(d - d0) * DSTATE];
  float corr = 0.f;
  #pragma unroll
  for (int q = 0; q < 4; ++q) {
    const float4 hv = hin4[q];
    const float4 cv = Ct4[q];
    corr = fmaf(__expf(Ar[4*q+0] * cum) * hv.x, cv.x, corr);
    corr = fmaf(__expf(Ar[4*q+1] * cum) * hv.y, cv.y, corr);
    corr = fmaf(__expf(Ar[4*q+2] * cum) * hv.z, cv.z, corr);
    corr = fmaf(__expf(Ar[4*q+3] * cum) * hv.w, cv.w, corr);
  }
  const float xv = xc2[idx], zv = zbuf[idx];
  y[idx] = (y[idx] + corr + xv * Dp[d]) * silu_f(zv);
}

extern "C" void kernel_launch(void* const* d_in, const int* in_sizes, int n_in,
                              void* d_out, int out_size, void* d_ws, size_t ws_size,
                              hipStream_t stream) {
  const float* x      = (const float*)d_in[0];
  const float* W_in   = (const float*)d_in[1];
  const float* conv_w = (const float*)d_in[2];
  const float* conv_b = (const float*)d_in[3];
  const float* W_xproj= (const float*)d_in[4];
  const float* W_dt   = (const float*)d_in[5];
  const float* b_dt   = (const float*)d_in[6];
  const float* A_log  = (const float*)d_in[7];
  const float* Dp     = (const float*)d_in[8];
  const float* W_out  = (const float*)d_in[9];
  float* out = (float*)d_out;
  float* ws  = (float*)d_ws;

  // ws layout (floats), 138 MB — proven round-3/5 footprint:
  //   xc_raw[SEG] | zbuf[SEG] | xc2[SEG] | dtb[SEG] | xp | hloc | totdt
  // Overlays (time-disjoint):
  //   stage-1 bf16 pool (xhi,xlo,Whi,Wlo) over dtb (dead until GEMM3)
  //   stage-4 bf16 pool (yhi,ylo,Wohi,Wolo) over zbuf+xc2 (dead after scan_fix)
  //   y reuses xc_raw (dead after conv)
  const size_t SEG = (size_t)NB * LSEQ * DI;            // 8,388,608
  float* xc_raw = ws;
  float* zbuf   = ws + SEG;
  float* xc2    = ws + 2 * SEG;
  float* dtb    = ws + 3 * SEG;
  float* xp     = ws + 4 * SEG;                         // 393,216
  float* hloc   = xp + (size_t)MROWS * NXP;             // 524,288
  float* totdt  = hloc + (size_t)NB * CHUNKS * DI * DSTATE;  // 32,768

  unsigned short* xhi = (unsigned short*)dtb;
  unsigned short* xlo = xhi + (size_t)MROWS * DMODEL;
  unsigned short* Whi = xlo + (size_t)MROWS * DMODEL;
  unsigned short* Wlo = Whi + (size_t)2 * DI * DMODEL;

  unsigned short* yhi  = (unsigned short*)zbuf;
  unsigned short* ylo  = yhi + SEG;
  unsigned short* Wohi = ylo + SEG;
  unsigned short* Wolo = Wohi + (size_t)DMODEL * DI;

  float* yb = xc_raw;
  dim3 blk(256);

  // Convert x and W_in to bf16 hi/lo
  split_bf16_kernel<<<(MROWS*DMODEL/4 + 255)/256, blk, 0, stream>>>(x, xhi, xlo, MROWS*DMODEL/4);
  split_bf16_kernel<<<(2*DI*DMODEL/4 + 255)/256, blk, 0, stream>>>(W_in, Whi, Wlo, 2*DI*DMODEL/4);

  // GEMM1 fused: [xc | z] = x @ W_in^T  (M=4096, N=4096 over two C buffers, K=1024)
  gemm_bf16x3<false><<<dim3(2*DI/128, MROWS/128, 1), blk, 0, stream>>>(
      xhi, xlo, Whi, Wlo, xc_raw, zbuf, DI, DMODEL, DMODEL);

  // conv + bias + SiLU
  conv_silu_kernel<<<(NB*LSEQ*DI)/256, blk, 0, stream>>>(xc_raw, conv_w, conv_b, xc2);

  // GEMM2: xp = xc2 @ W_xproj^T  (N=96) — split-K=8 fp32, atomic accumulate
  hipMemsetAsync(xp, 0, (size_t)MROWS * NXP * sizeof(float), stream);
  gemm_nt_splitk<<<dim3(1, MROWS/128, 8), blk, 0, stream>>>(
      xc2, W_xproj, xp, NXP, DI, DI, NXP, DI/8);

  // GEMM3: dt = softplus(dt_lr @ W_dt^T + b_dt)  (fp32, K=64; dtb overlay dead now)
  gemm_nt<1><<<dim3(DI/128, MROWS/128), blk, 0, stream>>>(
      xp, W_dt, b_dt, dtb, DI, DTRANK, NXP, DTRANK, DI);

  // Chunked scan -> yb
  scan_chunk_kernel<<<dim3(DI/16, NB, CHUNKS), blk, 0, stream>>>(
      xc2, dtb, xp, A_log, yb, hloc, totdt);
  scan_carry_kernel<<<(NB*DI*DSTATE)/256, blk, 0, stream>>>(hloc, totdt, A_log);
  scan_fix_kernel<<<(NB*LSEQ*DI)/256, blk, 0, stream>>>(
      xc2, dtb, xp, zbuf, A_log, Dp, hloc, yb);

  // Convert y and W_out; GEMM4: out = y @ W_out^T — split-K=2, atomic epilogue
  split_bf16_kernel<<<(NB*LSEQ*DI/4 + 255)/256, blk, 0, stream>>>(yb, yhi, ylo, NB*LSEQ*DI/4);
  split_bf16_kernel<<<(DMODEL*DI/4 + 255)/256, blk, 0, stream>>>(W_out, Wohi, Wolo, DMODEL*DI/4);
  hipMemsetAsync(out, 0, (size_t)MROWS * DMODEL * sizeof(float), stream);
  gemm_bf16x3<true><<<dim3(DMODEL/128, MROWS/128, 2), blk, 0, stream>>>(
      yhi, ylo, Wohi, Wolo, out, out, DMODEL, DI, DI/2);
}

// Round 7
// 620.292 us; speedup vs baseline: 3.6953x; 1.1801x over previous
//
#include <hip/hip_runtime.h>
#include <cstddef>
#include <cstdint>

// Problem constants (match reference)
#define DMODEL 1024
#define DI     2048      // D_INNER
#define LSEQ   2048
#define NB     2
#define DSTATE 16
#define DTRANK 64
#define NXP    96        // DT_RANK + 2*D_STATE
#define MROWS  (NB*LSEQ) // 4096 GEMM rows
#define CHUNKS 32
#define LC     (LSEQ/CHUNKS)   // 64

typedef __attribute__((ext_vector_type(8))) short bf16x8;
typedef __attribute__((ext_vector_type(4))) float f32x4;

__device__ __forceinline__ float silu_f(float v) {
  return v / (1.f + __expf(-v));
}
__device__ __forceinline__ float softplus_f(float v) {
  return (v > 20.f) ? v : log1pf(__expf(v));
}
__device__ __forceinline__ unsigned short f2bf(float f) {   // RNE
  unsigned u = __float_as_uint(f);
  unsigned r = (u + 0x7FFFu + ((u >> 16) & 1u)) >> 16;
  return (unsigned short)r;
}
__device__ __forceinline__ float bf2f(unsigned short h) {
  return __uint_as_float(((unsigned)h) << 16);
}
__device__ __forceinline__ void gl2lds16(const void* g, void* l) {
  __builtin_amdgcn_global_load_lds(
      (const __attribute__((address_space(1))) void*)g,
      (__attribute__((address_space(3))) void*)l, 16, 0, 0);
}

// fp32 -> (bf16 hi, bf16 lo), 4 elements/thread
__global__ __launch_bounds__(256)
void split_bf16_kernel(const float* __restrict__ in, unsigned short* __restrict__ hi,
                       unsigned short* __restrict__ lo, int n4) {
  int i = blockIdx.x * 256 + threadIdx.x;
  if (i >= n4) return;
  float4 v = ((const float4*)in)[i];
  ushort4 h, l;
  h.x = f2bf(v.x); h.y = f2bf(v.y); h.z = f2bf(v.z); h.w = f2bf(v.w);
  l.x = f2bf(v.x - bf2f(h.x)); l.y = f2bf(v.y - bf2f(h.y));
  l.z = f2bf(v.z - bf2f(h.z)); l.w = f2bf(v.w - bf2f(h.w));
  ((ushort4*)hi)[i] = h; ((ushort4*)lo)[i] = l;
}

// C[m,n] = sum_k A[m,k]*B[n,k] in bf16x3 (Ahi*Bhi + Ahi*Blo + Alo*Bhi).
// 128x128 tile, 256 threads (4 waves, 2x2 of 64x64), BK=64, 16x16x32 MFMA.
// global_load_lds (16B) staging + 16B-granule XOR swizzle -> conflict-free
// ds_read_b128. Dual-output: block cols [0,NC)->C0, [NC,2NC)->C1. Split-K via
// blockIdx.z; ATOMIC accumulates with atomicAdd.
template<bool ATOMIC>
__global__ __launch_bounds__(256)
void gemm_bf16x3(const unsigned short* __restrict__ Ahi, const unsigned short* __restrict__ Alo,
                 const unsigned short* __restrict__ Bhi, const unsigned short* __restrict__ Blo,
                 float* __restrict__ C0, float* __restrict__ C1,
                 int NC, int K, int klen) {
  __shared__ __align__(16) unsigned short Asl[128 * 64];
  __shared__ __align__(16) unsigned short Bsl[128 * 64];
  const int tid  = threadIdx.x;
  const int lane = tid & 63;
  const int wv   = tid >> 6;
  const int wm   = wv >> 1, wn = wv & 1;
  const int quad = lane >> 4, lr = lane & 15;
  const int bm = blockIdx.y * 128, bn = blockIdx.x * 128;
  const int kbeg = blockIdx.z * klen, kend = kbeg + klen;

  int aOffE[4], bOffE[4], ldsOff[4];
  #pragma unroll
  for (int j = 0; j < 4; ++j) {
    const int s   = (wv * 4 + j) * 64 + lane;
    const int row = s >> 3;
    const int c   = (s & 7) ^ (row & 7);
    aOffE[j]  = (bm + row) * K + c * 8;
    bOffE[j]  = (bn + row) * K + c * 8;
    ldsOff[j] = (wv * 4 + j) << 10;
  }
  int aRd[2][4], bRd[2][4];
  #pragma unroll
  for (int kk2 = 0; kk2 < 2; ++kk2)
    #pragma unroll
    for (int i = 0; i < 4; ++i) {
      const int ra = wm * 64 + i * 16 + lr;
      aRd[kk2][i] = ((ra << 3) + ((kk2 * 4 + quad) ^ (ra & 7))) << 4;
      const int rb = wn * 64 + i * 16 + lr;
      bRd[kk2][i] = ((rb << 3) + ((kk2 * 4 + quad) ^ (rb & 7))) << 4;
    }

  f32x4 acc[4][4];
  #pragma unroll
  for (int i = 0; i < 4; ++i)
    #pragma unroll
    for (int j = 0; j < 4; ++j)
      acc[i][j] = (f32x4){0.f, 0.f, 0.f, 0.f};

  #pragma unroll 1
  for (int ph = 0; ph < 3; ++ph) {
    const unsigned short* Ap = (ph == 2) ? Alo : Ahi;
    const unsigned short* Bp = (ph == 1) ? Blo : Bhi;
    #pragma unroll 1
    for (int km = kbeg; km < kend; km += 64) {
      #pragma unroll
      for (int j = 0; j < 4; ++j) {
        gl2lds16(Ap + (size_t)aOffE[j] + km, (char*)Asl + ldsOff[j]);
        gl2lds16(Bp + (size_t)bOffE[j] + km, (char*)Bsl + ldsOff[j]);
      }
      __syncthreads();
      bf16x8 af[2][4], bfv[2][4];
      #pragma unroll
      for (int kk2 = 0; kk2 < 2; ++kk2)
        #pragma unroll
        for (int i = 0; i < 4; ++i) {
          af[kk2][i]  = *(const bf16x8*)((const char*)Asl + aRd[kk2][i]);
          bfv[kk2][i] = *(const bf16x8*)((const char*)Bsl + bRd[kk2][i]);
        }
      #pragma unroll
      for (int kk2 = 0; kk2 < 2; ++kk2)
        #pragma unroll
        for (int i = 0; i < 4; ++i)
          #pragma unroll
          for (int j = 0; j < 4; ++j)
            acc[i][j] = __builtin_amdgcn_mfma_f32_16x16x32_bf16(
                af[kk2][i], bfv[kk2][j], acc[i][j], 0, 0, 0);
      __syncthreads();
    }
  }

  float* C = C0;
  int bnc = bn;
  if (bn >= NC) { C = C1; bnc = bn - NC; }

  #pragma unroll
  for (int i = 0; i < 4; ++i) {
    const int gr = bm + wm * 64 + i * 16 + quad * 4;
    #pragma unroll
    for (int j = 0; j < 4; ++j) {
      const int gc = bnc + wn * 64 + j * 16 + lr;
      float* cp = C + (size_t)gr * NC + gc;
      #pragma unroll
      for (int r = 0; r < 4; ++r) {
        if (ATOMIC) atomicAdd(&cp[(size_t)r * NC], acc[i][j][r]);
        else        cp[(size_t)r * NC] = acc[i][j][r];
      }
    }
  }
}

// fp32 GEMM (small shapes). C[m,n]=act(sum_k A[m,k]*B[n,k](+bias))
template<int ACT>
__global__ __launch_bounds__(256)
void gemm_nt(const float* __restrict__ A, const float* __restrict__ B,
             const float* __restrict__ bias, float* __restrict__ C,
             int N, int K, int lda, int ldb, int ldc) {
  __shared__ float As[16][132];
  __shared__ float Bs[16][132];
  const int tid = threadIdx.x;
  const int bm = blockIdx.y * 128, bn = blockIdx.x * 128;
  const int r  = tid >> 2;
  const int c4 = (tid & 3) << 2;
  const int ty = tid >> 4, tx = tid & 15;
  float acc[8][8];
  #pragma unroll
  for (int i = 0; i < 8; ++i)
    #pragma unroll
    for (int j = 0; j < 8; ++j) acc[i][j] = 0.f;

  for (int k0 = 0; k0 < K; k0 += 16) {
    float4 a0 = *(const float4*)(A + (size_t)(bm + r) * lda + k0 + c4);
    float4 a1 = *(const float4*)(A + (size_t)(bm + r + 64) * lda + k0 + c4);
    float4 b0 = make_float4(0.f, 0.f, 0.f, 0.f);
    float4 b1 = make_float4(0.f, 0.f, 0.f, 0.f);
    if (bn + r < N)      b0 = *(const float4*)(B + (size_t)(bn + r) * ldb + k0 + c4);
    if (bn + r + 64 < N) b1 = *(const float4*)(B + (size_t)(bn + r + 64) * ldb + k0 + c4);
    As[c4+0][r]    = a0.x; As[c4+1][r]    = a0.y; As[c4+2][r]    = a0.z; As[c4+3][r]    = a0.w;
    As[c4+0][r+64] = a1.x; As[c4+1][r+64] = a1.y; As[c4+2][r+64] = a1.z; As[c4+3][r+64] = a1.w;
    Bs[c4+0][r]    = b0.x; Bs[c4+1][r]    = b0.y; Bs[c4+2][r]    = b0.z; Bs[c4+3][r]    = b0.w;
    Bs[c4+0][r+64] = b1.x; Bs[c4+1][r+64] = b1.y; Bs[c4+2][r+64] = b1.z; Bs[c4+3][r+64] = b1.w;
    __syncthreads();
    #pragma unroll
    for (int k = 0; k < 16; ++k) {
      float4 av0 = *(const float4*)&As[k][ty*4];
      float4 av1 = *(const float4*)&As[k][64 + ty*4];
      float4 bv0 = *(const float4*)&Bs[k][tx*4];
      float4 bv1 = *(const float4*)&Bs[k][64 + tx*4];
      float a[8] = {av0.x, av0.y, av0.z, av0.w, av1.x, av1.y, av1.z, av1.w};
      float b[8] = {bv0.x, bv0.y, bv0.z, bv0.w, bv1.x, bv1.y, bv1.z, bv1.w};
      #pragma unroll
      for (int i = 0; i < 8; ++i)
        #pragma unroll
        for (int j = 0; j < 8; ++j)
          acc[i][j] = fmaf(a[i], b[j], acc[i][j]);
    }
    __syncthreads();
  }
  #pragma unroll
  for (int i = 0; i < 8; ++i) {
    const int m = bm + ty * 4 + (i & 3) + ((i >= 4) ? 64 : 0);
    #pragma unroll
    for (int j = 0; j < 8; ++j) {
      const int n = bn + tx * 4 + (j & 3) + ((j >= 4) ? 64 : 0);
      if (n < N) {
        float v = acc[i][j];
        if (ACT == 1) v = softplus_f(v + bias[n]);
        C[(size_t)m * ldc + n] = v;
      }
    }
  }
}

// Split-K fp32 GEMM, atomicAdd epilogue (C pre-zeroed).
__global__ __launch_bounds__(256)
void gemm_nt_splitk(const float* __restrict__ A, const float* __restrict__ B,
                    float* __restrict__ C,
                    int N, int lda, int ldb, int ldc, int kslice) {
  __shared__ float As[16][132];
  __shared__ float Bs[16][132];
  const int tid = threadIdx.x;
  const int bm = blockIdx.y * 128, bn = blockIdx.x * 128;
  const int kbeg = blockIdx.z * kslice, kend = kbeg + kslice;
  const int r  = tid >> 2;
  const int c4 = (tid & 3) << 2;
  const int ty = tid >> 4, tx = tid & 15;
  float acc[8][8];
  #pragma unroll
  for (int i = 0; i < 8; ++i)
    #pragma unroll
    for (int j = 0; j < 8; ++j) acc[i][j] = 0.f;

  for (int k0 = kbeg; k0 < kend; k0 += 16) {
    float4 a0 = *(const float4*)(A + (size_t)(bm + r) * lda + k0 + c4);
    float4 a1 = *(const float4*)(A + (size_t)(bm + r + 64) * lda + k0 + c4);
    float4 b0 = make_float4(0.f, 0.f, 0.f, 0.f);
    float4 b1 = make_float4(0.f, 0.f, 0.f, 0.f);
    if (bn + r < N)      b0 = *(const float4*)(B + (size_t)(bn + r) * ldb + k0 + c4);
    if (bn + r + 64 < N) b1 = *(const float4*)(B + (size_t)(bn + r + 64) * ldb + k0 + c4);
    As[c4+0][r]    = a0.x; As[c4+1][r]    = a0.y; As[c4+2][r]    = a0.z; As[c4+3][r]    = a0.w;
    As[c4+0][r+64] = a1.x; As[c4+1][r+64] = a1.y; As[c4+2][r+64] = a1.z; As[c4+3][r+64] = a1.w;
    Bs[c4+0][r]    = b0.x; Bs[c4+1][r]    = b0.y; Bs[c4+2][r]    = b0.z; Bs[c4+3][r]    = b0.w;
    Bs[c4+0][r+64] = b1.x; Bs[c4+1][r+64] = b1.y; Bs[c4+2][r+64] = b1.z; Bs[c4+3][r+64] = b1.w;
    __syncthreads();
    #pragma unroll
    for (int k = 0; k < 16; ++k) {
      float4 av0 = *(const float4*)&As[k][ty*4];
      float4 av1 = *(const float4*)&As[k][64 + ty*4];
      float4 bv0 = *(const float4*)&Bs[k][tx*4];
      float4 bv1 = *(const float4*)&Bs[k][64 + tx*4];
      float a[8] = {av0.x, av0.y, av0.z, av0.w, av1.x, av1.y, av1.z, av1.w};
      float b[8] = {bv0.x, bv0.y, bv0.z, bv0.w, bv1.x, bv1.y, bv1.z, bv1.w};
      #pragma unroll
      for (int i = 0; i < 8; ++i)
        #pragma unroll
        for (int j = 0; j < 8; ++j)
          acc[i][j] = fmaf(a[i], b[j], acc[i][j]);
    }
    __syncthreads();
  }
  #pragma unroll
  for (int i = 0; i < 8; ++i) {
    const int m = bm + ty * 4 + (i & 3) + ((i >= 4) ? 64 : 0);
    #pragma unroll
    for (int j = 0; j < 8; ++j) {
      const int n = bn + tx * 4 + (j & 3) + ((j >= 4) ? 64 : 0);
      if (n < N) atomicAdd(&C[(size_t)m * ldc + n], acc[i][j]);
    }
  }
}

// Causal depthwise conv (width 4) + bias + SiLU.  xc2[b,l,d]
__global__ __launch_bounds__(256)
void conv_silu_kernel(const float* __restrict__ xc_raw, const float* __restrict__ cw,
                      const float* __restrict__ cb, float* __restrict__ xc2) {
  const int idx = blockIdx.x * 256 + threadIdx.x;
  const int d = idx & (DI - 1);
  const int l = (idx >> 11) & (LSEQ - 1);
  const int b = idx >> 22;
  float acc = cb[d];
  #pragma unroll
  for (int j = 0; j < 4; ++j) {
    const int ls = l - 3 + j;
    if (ls >= 0)
      acc = fmaf(xc_raw[((size_t)b * LSEQ + ls) * DI + d], cw[d * 4 + j], acc);
  }
  xc2[idx] = silu_f(acc);
}

// ---- Chunked selective scan, serial-state layout ----
// Pass 1: one THREAD per (b,d,chunk); all 16 states in registers. B/C staged
// once per chunk in LDS (broadcast reads). dt/x coalesced across consecutive d,
// prefetched U=4 ahead. y-dot via binary tree (no cross-lane ops).
// hloc layout: [b][chunk][n][d] (coalesced stores/loads).
__global__ __launch_bounds__(256)
void scan_chunk_kernel(const float* __restrict__ xc2, float* __restrict__ dtb,
                       const float* __restrict__ xp, const float* __restrict__ A_log,
                       float* __restrict__ y_local, float* __restrict__ hloc,
                       float* __restrict__ totdt) {
  __shared__ float sbc[LC][32];   // 8 KB: [t][0:16)=B, [16:32)=C
  const int d = blockIdx.x * 256 + threadIdx.x;
  const int b = blockIdx.y;
  const int c = blockIdx.z;

  float A[DSTATE], h[DSTATE];
  #pragma unroll
  for (int n = 0; n < DSTATE; ++n) {
    A[n] = -__expf(A_log[(size_t)d * DSTATE + n]);
    h[n] = 0.f;
  }

  // Stage B/C for this chunk: LC*32 = 2048 floats, 2 float4 per thread.
  const float* xpb = xp + ((size_t)b * LSEQ + (size_t)c * LC) * NXP + DTRANK;
  #pragma unroll
  for (int kk = 0; kk < 2; ++kk) {
    const int slot = threadIdx.x + kk * 256;   // 512 float4 slots
    const int row = slot >> 3, c4 = (slot & 7) << 2;
    *(float4*)&sbc[row][c4] = *(const float4*)&xpb[(size_t)row * NXP + c4];
  }
  __syncthreads();

  const size_t cbase = ((size_t)b * LSEQ + (size_t)c * LC) * DI + d;
  float cum = 0.f;
  constexpr int U = 4;
  float cdt[U], cx[U];
  #pragma unroll
  for (int u = 0; u < U; ++u) {
    cdt[u] = dtb[cbase + (size_t)u * DI];
    cx[u]  = xc2[cbase + (size_t)u * DI];
  }

  #pragma unroll 1
  for (int g = 0; g < LC; g += U) {
    float ndt[U], nx[U];
    if (g + U < LC) {
      #pragma unroll
      for (int u = 0; u < U; ++u) {
        ndt[u] = dtb[cbase + (size_t)(g + U + u) * DI];
        nx[u]  = xc2[cbase + (size_t)(g + U + u) * DI];
      }
    }
    #pragma unroll
    for (int u = 0; u < U; ++u) {
      const int t = g + u;
      const float dt = cdt[u];
      const float dx = dt * cx[u];
      cum += dt;
      #pragma unroll
      for (int n = 0; n < DSTATE; ++n) {
        const float ab = __expf(dt * A[n]);
        h[n] = fmaf(ab, h[n], dx * sbc[t][n]);
      }
      float p[DSTATE];
      #pragma unroll
      for (int n = 0; n < DSTATE; ++n) p[n] = h[n] * sbc[t][DSTATE + n];
      #pragma unroll
      for (int s = 1; s < DSTATE; s <<= 1)
        #pragma unroll
        for (int n = 0; n < DSTATE; n += 2 * s) p[n] += p[n + s];
      const size_t base = cbase + (size_t)t * DI;
      y_local[base] = p[0];
      dtb[base] = cum;               // overwrite dt with inclusive cumsum
    }
    #pragma unroll
    for (int u = 0; u < U; ++u) { cdt[u] = ndt[u]; cx[u] = nx[u]; }
  }

  const size_t hbase = ((size_t)(b * CHUNKS + c)) * DSTATE * DI + d;
  #pragma unroll
  for (int n = 0; n < DSTATE; ++n) hloc[hbase + (size_t)n * DI] = h[n];
  totdt[((size_t)(b * CHUNKS + c)) * DI + d] = cum;
}

// Pass 2: carry propagation. One thread per (b,n,d); 1-chunk prefetch.
__global__ __launch_bounds__(256)
void scan_carry_kernel(float* __restrict__ hloc, const float* __restrict__ totdt,
                       const float* __restrict__ A_log) {
  const int tid = blockIdx.x * 256 + threadIdx.x;   // NB*DSTATE*DI
  const int d = tid & (DI - 1);
  const int n = (tid >> 11) & 15;
  const int b = tid >> 15;
  const float An = -__expf(A_log[(size_t)d * DSTATE + n]);
  float h = 0.f;
  float le = hloc[((size_t)(b * CHUNKS) * DSTATE + n) * DI + d];
  float td = totdt[(size_t)(b * CHUNKS) * DI + d];
  for (int c = 0; c < CHUNKS; ++c) {
    const size_t ix = ((size_t)(b * CHUNKS + c) * DSTATE + n) * DI + d;
    float nle = 0.f, ntd = 0.f;
    if (c + 1 < CHUNKS) {
      nle = hloc[ix + (size_t)DSTATE * DI];
      ntd = totdt[(size_t)(b * CHUNKS + c + 1) * DI + d];
    }
    hloc[ix] = h;                        // h entering chunk c
    h = fmaf(__expf(An * td), h, le);    // h entering chunk c+1
    le = nle; td = ntd;
  }
}

// Pass 3: correction + epilogue.  hloc layout [b][c][n][d].
__global__ __launch_bounds__(256)
void scan_fix_kernel(const float* __restrict__ xc2, const float* __restrict__ dtb,
                     const float* __restrict__ xp, const float* __restrict__ zbuf,
                     const float* __restrict__ A_log, const float* __restrict__ Dp,
                     const float* __restrict__ hloc, float* __restrict__ y) {
  __shared__ float sA[256 * DSTATE];
  const int tid = threadIdx.x;
  const int idx = blockIdx.x * 256 + tid;
  const int d = idx & (DI - 1);
  const int l = (idx >> 11) & (LSEQ - 1);
  const int b = idx >> 22;
  const int d0 = (blockIdx.x & ((DI / 256) - 1)) * 256;
  for (int i = tid; i < 256 * DSTATE; i += 256)
    sA[i] = -__expf(A_log[(size_t)d0 * DSTATE + i]);
  __syncthreads();

  const int c = l / LC;
  const float cum = dtb[idx];
  const float* hp = hloc + ((size_t)(b * CHUNKS + c)) * DSTATE * DI + d;
  const float4* Ct4 = (const float4*)&xp[((size_t)b * LSEQ + l) * NXP + DTRANK + DSTATE];
  const float* Ar = &sA[(d - d0) * DSTATE];
  float Ct[DSTATE];
  #pragma unroll
  for (int q = 0; q < 4; ++q) {
    const float4 cv = Ct4[q];
    Ct[4*q+0] = cv.x; Ct[4*q+1] = cv.y; Ct[4*q+2] = cv.z; Ct[4*q+3] = cv.w;
  }
  float corr = 0.f;
  #pragma unroll
  for (int n = 0; n < DSTATE; ++n)
    corr = fmaf(__expf(Ar[n] * cum) * hp[(size_t)n * DI], Ct[n], corr);
  const float xv = xc2[idx], zv = zbuf[idx];
  y[idx] = (y[idx] + corr + xv * Dp[d]) * silu_f(zv);
}

extern "C" void kernel_launch(void* const* d_in, const int* in_sizes, int n_in,
                              void* d_out, int out_size, void* d_ws, size_t ws_size,
                              hipStream_t stream) {
  const float* x      = (const float*)d_in[0];
  const float* W_in   = (const float*)d_in[1];
  const float* conv_w = (const float*)d_in[2];
  const float* conv_b = (const float*)d_in[3];
  const float* W_xproj= (const float*)d_in[4];
  const float* W_dt   = (const float*)d_in[5];
  const float* b_dt   = (const float*)d_in[6];
  const float* A_log  = (const float*)d_in[7];
  const float* Dp     = (const float*)d_in[8];
  const float* W_out  = (const float*)d_in[9];
  float* out = (float*)d_out;
  float* ws  = (float*)d_ws;

  // ws layout (floats), ~145 MB:
  //   xc_raw[SEG] | zbuf[SEG] | xc2[SEG] | dtb[SEG] | xp | hloc[2.1M] | totdt[131k]
  // Overlays (time-disjoint):
  //   stage-1 bf16 pool (xhi,xlo,Whi,Wlo = SEG floats) over dtb (dead until GEMM3)
  //   stage-4 bf16 pool (yhi,ylo,Wohi,Wolo) over zbuf+xc2 (dead after scan_fix)
  //   y reuses xc_raw (dead after conv)
  const size_t SEG = (size_t)NB * LSEQ * DI;            // 8,388,608
  float* xc_raw = ws;
  float* zbuf   = ws + SEG;
  float* xc2    = ws + 2 * SEG;
  float* dtb    = ws + 3 * SEG;
  float* xp     = ws + 4 * SEG;                         // 393,216
  float* hloc   = xp + (size_t)MROWS * NXP;             // NB*CHUNKS*DSTATE*DI = 2,097,152
  float* totdt  = hloc + (size_t)NB * CHUNKS * DSTATE * DI;  // 131,072

  unsigned short* xhi = (unsigned short*)dtb;
  unsigned short* xlo = xhi + (size_t)MROWS * DMODEL;
  unsigned short* Whi = xlo + (size_t)MROWS * DMODEL;
  unsigned short* Wlo = Whi + (size_t)2 * DI * DMODEL;

  unsigned short* yhi  = (unsigned short*)zbuf;
  unsigned short* ylo  = yhi + SEG;
  unsigned short* Wohi = ylo + SEG;
  unsigned short* Wolo = Wohi + (size_t)DMODEL * DI;

  float* yb = xc_raw;
  dim3 blk(256);

  // Convert x and W_in to bf16 hi/lo
  split_bf16_kernel<<<(MROWS*DMODEL/4 + 255)/256, blk, 0, stream>>>(x, xhi, xlo, MROWS*DMODEL/4);
  split_bf16_kernel<<<(2*DI*DMODEL/4 + 255)/256, blk, 0, stream>>>(W_in, Whi, Wlo, 2*DI*DMODEL/4);

  // GEMM1 fused: [xc | z] = x @ W_in^T  (M=4096, N=4096 over two C buffers, K=1024)
  gemm_bf16x3<false><<<dim3(2*DI/128, MROWS/128, 1), blk, 0, stream>>>(
      xhi, xlo, Whi, Wlo, xc_raw, zbuf, DI, DMODEL, DMODEL);

  // conv + bias + SiLU
  conv_silu_kernel<<<(NB*LSEQ*DI)/256, blk, 0, stream>>>(xc_raw, conv_w, conv_b, xc2);

  // GEMM2: xp = xc2 @ W_xproj^T  (N=96) — split-K=8 fp32, atomic accumulate
  hipMemsetAsync(xp, 0, (size_t)MROWS * NXP * sizeof(float), stream);
  gemm_nt_splitk<<<dim3(1, MROWS/128, 8), blk, 0, stream>>>(
      xc2, W_xproj, xp, NXP, DI, DI, NXP, DI/8);

  // GEMM3: dt = softplus(dt_lr @ W_dt^T + b_dt)  (fp32, K=64; dtb overlay dead now)
  gemm_nt<1><<<dim3(DI/128, MROWS/128), blk, 0, stream>>>(
      xp, W_dt, b_dt, dtb, DI, DTRANK, NXP, DTRANK, DI);

  // Chunked scan -> yb
  scan_chunk_kernel<<<dim3(DI/256, NB, CHUNKS), blk, 0, stream>>>(
      xc2, dtb, xp, A_log, yb, hloc, totdt);
  scan_carry_kernel<<<(NB*DI*DSTATE)/256, blk, 0, stream>>>(hloc, totdt, A_log);
  scan_fix_kernel<<<(NB*LSEQ*DI)/256, blk, 0, stream>>>(
      xc2, dtb, xp, zbuf, A_log, Dp, hloc, yb);

  // Convert y and W_out; GEMM4: out = y @ W_out^T — split-K=2, atomic epilogue
  split_bf16_kernel<<<(NB*LSEQ*DI/4 + 255)/256, blk, 0, stream>>>(yb, yhi, ylo, NB*LSEQ*DI/4);
  split_bf16_kernel<<<(DMODEL*DI/4 + 255)/256, blk, 0, stream>>>(W_out, Wohi, Wolo, DMODEL*DI/4);
  hipMemsetAsync(out, 0, (size_t)MROWS * DMODEL * sizeof(float), stream);
  gemm_bf16x3<true><<<dim3(DMODEL/128, MROWS/128, 2), blk, 0, stream>>>(
      yhi, ylo, Wohi, Wolo, out, out, DMODEL, DI, DI/2);
}

// Round 8
// 601.996 us; speedup vs baseline: 3.8076x; 1.0304x over previous
//
#include <hip/hip_runtime.h>
#include <cstddef>
#include <cstdint>

// Problem constants (match reference)
#define DMODEL 1024
#define DI     2048      // D_INNER
#define LSEQ   2048
#define NB     2
#define DSTATE 16
#define DTRANK 64
#define NXP    96        // DT_RANK + 2*D_STATE
#define MROWS  (NB*LSEQ) // 4096 GEMM rows
#define CHUNKS 32
#define LC     (LSEQ/CHUNKS)   // 64

typedef __attribute__((ext_vector_type(8))) short bf16x8;
typedef __attribute__((ext_vector_type(4))) float f32x4;

__device__ __forceinline__ float silu_f(float v) {
  return v / (1.f + __expf(-v));
}
__device__ __forceinline__ float softplus_f(float v) {
  return (v > 20.f) ? v : log1pf(__expf(v));
}
__device__ __forceinline__ unsigned short f2bf(float f) {   // RNE
  unsigned u = __float_as_uint(f);
  unsigned r = (u + 0x7FFFu + ((u >> 16) & 1u)) >> 16;
  return (unsigned short)r;
}
__device__ __forceinline__ float bf2f(unsigned short h) {
  return __uint_as_float(((unsigned)h) << 16);
}
__device__ __forceinline__ void gl2lds16(const void* g, void* l) {
  __builtin_amdgcn_global_load_lds(
      (const __attribute__((address_space(1))) void*)g,
      (__attribute__((address_space(3))) void*)l, 16, 0, 0);
}

// fp32 -> (bf16 hi, bf16 lo), 4 elements/thread
__global__ __launch_bounds__(256)
void split_bf16_kernel(const float* __restrict__ in, unsigned short* __restrict__ hi,
                       unsigned short* __restrict__ lo, int n4) {
  int i = blockIdx.x * 256 + threadIdx.x;
  if (i >= n4) return;
  float4 v = ((const float4*)in)[i];
  ushort4 h, l;
  h.x = f2bf(v.x); h.y = f2bf(v.y); h.z = f2bf(v.z); h.w = f2bf(v.w);
  l.x = f2bf(v.x - bf2f(h.x)); l.y = f2bf(v.y - bf2f(h.y));
  l.z = f2bf(v.z - bf2f(h.z)); l.w = f2bf(v.w - bf2f(h.w));
  ((ushort4*)hi)[i] = h; ((ushort4*)lo)[i] = l;
}

// dt_lr extract+split: xp[:, 0:64] (ld=96) -> packed 4096x64 hi/lo
__global__ __launch_bounds__(256)
void split_dtlr_kernel(const float* __restrict__ xp, unsigned short* __restrict__ hi,
                       unsigned short* __restrict__ lo) {
  const int i = blockIdx.x * 256 + threadIdx.x;   // MROWS*16 float4 slots
  const int r = i >> 4, c4 = (i & 15) << 2;
  float4 v = *(const float4*)&xp[(size_t)r * NXP + c4];
  ushort4 h, l;
  h.x = f2bf(v.x); h.y = f2bf(v.y); h.z = f2bf(v.z); h.w = f2bf(v.w);
  l.x = f2bf(v.x - bf2f(h.x)); l.y = f2bf(v.y - bf2f(h.y));
  l.z = f2bf(v.z - bf2f(h.z)); l.w = f2bf(v.w - bf2f(h.w));
  const int o = (r * DTRANK + c4) >> 2;
  ((ushort4*)hi)[o] = h; ((ushort4*)lo)[o] = l;
}

// C[m,n] = act( sum_k A[m,k]*B[n,k] ) in bf16x3 (Ahi*Bhi + Ahi*Blo + Alo*Bhi).
// Single-pass K-loop: BK=32, all FOUR tiles (Ahi,Alo,Bhi,Blo; 4x8KB = 32KB LDS)
// staged per K-block; 48 MFMAs + 16 ds_read_b128 per barrier pair (vs 32/16 x3
// phases before). Swizzle: granule c' = c ^ ((row>>1)&3) -> quarter-wave reads
// land 2-way per bank-group (free, m136). M,N mult of 128; K mult of 32.
// Dual-output cols [0,NC)->C0, [NC,2NC)->C1. Split-K via blockIdx.z.
// ACT=1: softplus(v + bias[col]).
template<bool ATOMIC, int ACT>
__global__ __launch_bounds__(256)
void gemm_bf16x3(const unsigned short* __restrict__ Ahi, const unsigned short* __restrict__ Alo,
                 const unsigned short* __restrict__ Bhi, const unsigned short* __restrict__ Blo,
                 const float* __restrict__ bias,
                 float* __restrict__ C0, float* __restrict__ C1,
                 int NC, int K, int klen) {
  __shared__ __align__(16) unsigned short Ah[128 * 32];
  __shared__ __align__(16) unsigned short Al[128 * 32];
  __shared__ __align__(16) unsigned short Bh[128 * 32];
  __shared__ __align__(16) unsigned short Bl[128 * 32];
  const int tid  = threadIdx.x;
  const int lane = tid & 63;
  const int wv   = tid >> 6;
  const int wm   = wv >> 1, wn = wv & 1;
  const int quad = lane >> 4, lr = lane & 15;
  const int bm = blockIdx.y * 128, bn = blockIdx.x * 128;
  const int kbeg = blockIdx.z * klen, kend = kbeg + klen;

  // Staging decode: slot s = (wv*2+j)*64 + lane; row = s>>2; c' = s&3;
  // global granule c = c' ^ ((row>>1)&3).
  int aOff[2], bOff[2], ldsO[2];
  #pragma unroll
  for (int j = 0; j < 2; ++j) {
    const int s   = (wv * 2 + j) * 64 + lane;
    const int row = s >> 2;
    const int c   = (s & 3) ^ ((row >> 1) & 3);
    aOff[j] = (bm + row) * K + c * 8;
    bOff[j] = (bn + row) * K + c * 8;
    ldsO[j] = (wv * 2 + j) << 10;   // 1 KB per wave-instr
  }
  // Fragment read byte offsets (swizzle-matched): (row*4 + (quad ^ ((row>>1)&3)))*16
  int aRd[4], bRd[4];
  #pragma unroll
  for (int i = 0; i < 4; ++i) {
    const int ra = wm * 64 + i * 16 + lr;
    aRd[i] = (ra * 4 + (quad ^ ((ra >> 1) & 3))) << 4;
    const int rb = wn * 64 + i * 16 + lr;
    bRd[i] = (rb * 4 + (quad ^ ((rb >> 1) & 3))) << 4;
  }

  f32x4 acc[4][4];
  #pragma unroll
  for (int i = 0; i < 4; ++i)
    #pragma unroll
    for (int j = 0; j < 4; ++j)
      acc[i][j] = (f32x4){0.f, 0.f, 0.f, 0.f};

  #pragma unroll 1
  for (int km = kbeg; km < kend; km += 32) {
    #pragma unroll
    for (int j = 0; j < 2; ++j) {
      gl2lds16(Ahi + (size_t)aOff[j] + km, (char*)Ah + ldsO[j]);
      gl2lds16(Alo + (size_t)aOff[j] + km, (char*)Al + ldsO[j]);
      gl2lds16(Bhi + (size_t)bOff[j] + km, (char*)Bh + ldsO[j]);
      gl2lds16(Blo + (size_t)bOff[j] + km, (char*)Bl + ldsO[j]);
    }
    __syncthreads();
    bf16x8 ah[4], al[4], bh[4], bl[4];
    #pragma unroll
    for (int i = 0; i < 4; ++i) {
      ah[i] = *(const bf16x8*)((const char*)Ah + aRd[i]);
      al[i] = *(const bf16x8*)((const char*)Al + aRd[i]);
      bh[i] = *(const bf16x8*)((const char*)Bh + bRd[i]);
      bl[i] = *(const bf16x8*)((const char*)Bl + bRd[i]);
    }
    #pragma unroll
    for (int i = 0; i < 4; ++i)
      #pragma unroll
      for (int j = 0; j < 4; ++j) {
        acc[i][j] = __builtin_amdgcn_mfma_f32_16x16x32_bf16(ah[i], bh[j], acc[i][j], 0, 0, 0);
        acc[i][j] = __builtin_amdgcn_mfma_f32_16x16x32_bf16(ah[i], bl[j], acc[i][j], 0, 0, 0);
        acc[i][j] = __builtin_amdgcn_mfma_f32_16x16x32_bf16(al[i], bh[j], acc[i][j], 0, 0, 0);
      }
    __syncthreads();
  }

  float* C = C0;
  int bnc = bn;
  if (bn >= NC) { C = C1; bnc = bn - NC; }

  // Epilogue: C/D layout col=lane&15, row=quad*4+reg  [m89-verified]
  #pragma unroll
  for (int i = 0; i < 4; ++i) {
    const int gr = bm + wm * 64 + i * 16 + quad * 4;
    #pragma unroll
    for (int j = 0; j < 4; ++j) {
      const int gc = bnc + wn * 64 + j * 16 + lr;
      float* cp = C + (size_t)gr * NC + gc;
      const float bv = (ACT == 1) ? bias[gc] : 0.f;
      #pragma unroll
      for (int r = 0; r < 4; ++r) {
        float v = acc[i][j][r];
        if (ACT == 1) v = softplus_f(v + bv);
        if (ATOMIC) atomicAdd(&cp[(size_t)r * NC], v);
        else        cp[(size_t)r * NC] = v;
      }
    }
  }
}

// Split-K fp32 GEMM, atomicAdd epilogue (C pre-zeroed). Used for GEMM2 (N=96).
__global__ __launch_bounds__(256)
void gemm_nt_splitk(const float* __restrict__ A, const float* __restrict__ B,
                    float* __restrict__ C,
                    int N, int lda, int ldb, int ldc, int kslice) {
  __shared__ float As[16][132];
  __shared__ float Bs[16][132];
  const int tid = threadIdx.x;
  const int bm = blockIdx.y * 128, bn = blockIdx.x * 128;
  const int kbeg = blockIdx.z * kslice, kend = kbeg + kslice;
  const int r  = tid >> 2;
  const int c4 = (tid & 3) << 2;
  const int ty = tid >> 4, tx = tid & 15;
  float acc[8][8];
  #pragma unroll
  for (int i = 0; i < 8; ++i)
    #pragma unroll
    for (int j = 0; j < 8; ++j) acc[i][j] = 0.f;

  for (int k0 = kbeg; k0 < kend; k0 += 16) {
    float4 a0 = *(const float4*)(A + (size_t)(bm + r) * lda + k0 + c4);
    float4 a1 = *(const float4*)(A + (size_t)(bm + r + 64) * lda + k0 + c4);
    float4 b0 = make_float4(0.f, 0.f, 0.f, 0.f);
    float4 b1 = make_float4(0.f, 0.f, 0.f, 0.f);
    if (bn + r < N)      b0 = *(const float4*)(B + (size_t)(bn + r) * ldb + k0 + c4);
    if (bn + r + 64 < N) b1 = *(const float4*)(B + (size_t)(bn + r + 64) * ldb + k0 + c4);
    As[c4+0][r]    = a0.x; As[c4+1][r]    = a0.y; As[c4+2][r]    = a0.z; As[c4+3][r]    = a0.w;
    As[c4+0][r+64] = a1.x; As[c4+1][r+64] = a1.y; As[c4+2][r+64] = a1.z; As[c4+3][r+64] = a1.w;
    Bs[c4+0][r]    = b0.x; Bs[c4+1][r]    = b0.y; Bs[c4+2][r]    = b0.z; Bs[c4+3][r]    = b0.w;
    Bs[c4+0][r+64] = b1.x; Bs[c4+1][r+64] = b1.y; Bs[c4+2][r+64] = b1.z; Bs[c4+3][r+64] = b1.w;
    __syncthreads();
    #pragma unroll
    for (int k = 0; k < 16; ++k) {
      float4 av0 = *(const float4*)&As[k][ty*4];
      float4 av1 = *(const float4*)&As[k][64 + ty*4];
      float4 bv0 = *(const float4*)&Bs[k][tx*4];
      float4 bv1 = *(const float4*)&Bs[k][64 + tx*4];
      float a[8] = {av0.x, av0.y, av0.z, av0.w, av1.x, av1.y, av1.z, av1.w};
      float b[8] = {bv0.x, bv0.y, bv0.z, bv0.w, bv1.x, bv1.y, bv1.z, bv1.w};
      #pragma unroll
      for (int i = 0; i < 8; ++i)
        #pragma unroll
        for (int j = 0; j < 8; ++j)
          acc[i][j] = fmaf(a[i], b[j], acc[i][j]);
    }
    __syncthreads();
  }
  #pragma unroll
  for (int i = 0; i < 8; ++i) {
    const int m = bm + ty * 4 + (i & 3) + ((i >= 4) ? 64 : 0);
    #pragma unroll
    for (int j = 0; j < 8; ++j) {
      const int n = bn + tx * 4 + (j & 3) + ((j >= 4) ? 64 : 0);
      if (n < N) atomicAdd(&C[(size_t)m * ldc + n], acc[i][j]);
    }
  }
}

// Causal depthwise conv (width 4) + bias + SiLU.  xc2[b,l,d]
__global__ __launch_bounds__(256)
void conv_silu_kernel(const float* __restrict__ xc_raw, const float* __restrict__ cw,
                      const float* __restrict__ cb, float* __restrict__ xc2) {
  const int idx = blockIdx.x * 256 + threadIdx.x;
  const int d = idx & (DI - 1);
  const int l = (idx >> 11) & (LSEQ - 1);
  const int b = idx >> 22;
  float acc = cb[d];
  #pragma unroll
  for (int j = 0; j < 4; ++j) {
    const int ls = l - 3 + j;
    if (ls >= 0)
      acc = fmaf(xc_raw[((size_t)b * LSEQ + ls) * DI + d], cw[d * 4 + j], acc);
  }
  xc2[idx] = silu_f(acc);
}

// ---- Chunked selective scan, serial-state layout (round-7, unchanged) ----
__global__ __launch_bounds__(256)
void scan_chunk_kernel(const float* __restrict__ xc2, float* __restrict__ dtb,
                       const float* __restrict__ xp, const float* __restrict__ A_log,
                       float* __restrict__ y_local, float* __restrict__ hloc,
                       float* __restrict__ totdt) {
  __shared__ float sbc[LC][32];   // 8 KB: [t][0:16)=B, [16:32)=C
  const int d = blockIdx.x * 256 + threadIdx.x;
  const int b = blockIdx.y;
  const int c = blockIdx.z;

  float A[DSTATE], h[DSTATE];
  #pragma unroll
  for (int n = 0; n < DSTATE; ++n) {
    A[n] = -__expf(A_log[(size_t)d * DSTATE + n]);
    h[n] = 0.f;
  }

  const float* xpb = xp + ((size_t)b * LSEQ + (size_t)c * LC) * NXP + DTRANK;
  #pragma unroll
  for (int kk = 0; kk < 2; ++kk) {
    const int slot = threadIdx.x + kk * 256;
    const int row = slot >> 3, c4 = (slot & 7) << 2;
    *(float4*)&sbc[row][c4] = *(const float4*)&xpb[(size_t)row * NXP + c4];
  }
  __syncthreads();

  const size_t cbase = ((size_t)b * LSEQ + (size_t)c * LC) * DI + d;
  float cum = 0.f;
  constexpr int U = 4;
  float cdt[U], cx[U];
  #pragma unroll
  for (int u = 0; u < U; ++u) {
    cdt[u] = dtb[cbase + (size_t)u * DI];
    cx[u]  = xc2[cbase + (size_t)u * DI];
  }

  #pragma unroll 1
  for (int g = 0; g < LC; g += U) {
    float ndt[U], nx[U];
    if (g + U < LC) {
      #pragma unroll
      for (int u = 0; u < U; ++u) {
        ndt[u] = dtb[cbase + (size_t)(g + U + u) * DI];
        nx[u]  = xc2[cbase + (size_t)(g + U + u) * DI];
      }
    }
    #pragma unroll
    for (int u = 0; u < U; ++u) {
      const int t = g + u;
      const float dt = cdt[u];
      const float dx = dt * cx[u];
      cum += dt;
      #pragma unroll
      for (int n = 0; n < DSTATE; ++n) {
        const float ab = __expf(dt * A[n]);
        h[n] = fmaf(ab, h[n], dx * sbc[t][n]);
      }
      float p[DSTATE];
      #pragma unroll
      for (int n = 0; n < DSTATE; ++n) p[n] = h[n] * sbc[t][DSTATE + n];
      #pragma unroll
      for (int s = 1; s < DSTATE; s <<= 1)
        #pragma unroll
        for (int n = 0; n < DSTATE; n += 2 * s) p[n] += p[n + s];
      const size_t base = cbase + (size_t)t * DI;
      y_local[base] = p[0];
      dtb[base] = cum;               // overwrite dt with inclusive cumsum
    }
    #pragma unroll
    for (int u = 0; u < U; ++u) { cdt[u] = ndt[u]; cx[u] = nx[u]; }
  }

  const size_t hbase = ((size_t)(b * CHUNKS + c)) * DSTATE * DI + d;
  #pragma unroll
  for (int n = 0; n < DSTATE; ++n) hloc[hbase + (size_t)n * DI] = h[n];
  totdt[((size_t)(b * CHUNKS + c)) * DI + d] = cum;
}

// Pass 2: carry propagation. One thread per (b,n,d); 1-chunk prefetch.
__global__ __launch_bounds__(256)
void scan_carry_kernel(float* __restrict__ hloc, const float* __restrict__ totdt,
                       const float* __restrict__ A_log) {
  const int tid = blockIdx.x * 256 + threadIdx.x;   // NB*DSTATE*DI
  const int d = tid & (DI - 1);
  const int n = (tid >> 11) & 15;
  const int b = tid >> 15;
  const float An = -__expf(A_log[(size_t)d * DSTATE + n]);
  float h = 0.f;
  float le = hloc[((size_t)(b * CHUNKS) * DSTATE + n) * DI + d];
  float td = totdt[(size_t)(b * CHUNKS) * DI + d];
  for (int c = 0; c < CHUNKS; ++c) {
    const size_t ix = ((size_t)(b * CHUNKS + c) * DSTATE + n) * DI + d;
    float nle = 0.f, ntd = 0.f;
    if (c + 1 < CHUNKS) {
      nle = hloc[ix + (size_t)DSTATE * DI];
      ntd = totdt[(size_t)(b * CHUNKS + c + 1) * DI + d];
    }
    hloc[ix] = h;
    h = fmaf(__expf(An * td), h, le);
    le = nle; td = ntd;
  }
}

// Pass 3: correction + epilogue.  hloc layout [b][c][n][d].
__global__ __launch_bounds__(256)
void scan_fix_kernel(const float* __restrict__ xc2, const float* __restrict__ dtb,
                     const float* __restrict__ xp, const float* __restrict__ zbuf,
                     const float* __restrict__ A_log, const float* __restrict__ Dp,
                     const float* __restrict__ hloc, float* __restrict__ y) {
  __shared__ float sA[256 * DSTATE];
  const int tid = threadIdx.x;
  const int idx = blockIdx.x * 256 + tid;
  const int d = idx & (DI - 1);
  const int l = (idx >> 11) & (LSEQ - 1);
  const int b = idx >> 22;
  const int d0 = (blockIdx.x & ((DI / 256) - 1)) * 256;
  for (int i = tid; i < 256 * DSTATE; i += 256)
    sA[i] = -__expf(A_log[(size_t)d0 * DSTATE + i]);
  __syncthreads();

  const int c = l / LC;
  const float cum = dtb[idx];
  const float* hp = hloc + ((size_t)(b * CHUNKS + c)) * DSTATE * DI + d;
  const float4* Ct4 = (const float4*)&xp[((size_t)b * LSEQ + l) * NXP + DTRANK + DSTATE];
  const float* Ar = &sA[(d - d0) * DSTATE];
  float Ct[DSTATE];
  #pragma unroll
  for (int q = 0; q < 4; ++q) {
    const float4 cv = Ct4[q];
    Ct[4*q+0] = cv.x; Ct[4*q+1] = cv.y; Ct[4*q+2] = cv.z; Ct[4*q+3] = cv.w;
  }
  float corr = 0.f;
  #pragma unroll
  for (int n = 0; n < DSTATE; ++n)
    corr = fmaf(__expf(Ar[n] * cum) * hp[(size_t)n * DI], Ct[n], corr);
  const float xv = xc2[idx], zv = zbuf[idx];
  y[idx] = (y[idx] + corr + xv * Dp[d]) * silu_f(zv);
}

extern "C" void kernel_launch(void* const* d_in, const int* in_sizes, int n_in,
                              void* d_out, int out_size, void* d_ws, size_t ws_size,
                              hipStream_t stream) {
  const float* x      = (const float*)d_in[0];
  const float* W_in   = (const float*)d_in[1];
  const float* conv_w = (const float*)d_in[2];
  const float* conv_b = (const float*)d_in[3];
  const float* W_xproj= (const float*)d_in[4];
  const float* W_dt   = (const float*)d_in[5];
  const float* b_dt   = (const float*)d_in[6];
  const float* A_log  = (const float*)d_in[7];
  const float* Dp     = (const float*)d_in[8];
  const float* W_out  = (const float*)d_in[9];
  float* out = (float*)d_out;
  float* ws  = (float*)d_ws;

  // ws layout (floats), ~147 MB (round-7 proven 145 MB + 1.5 MB dt pool):
  //   xc_raw[SEG] | zbuf[SEG] | xc2[SEG] | dtb[SEG] | xp | hloc[2.1M] | totdt[131k] | dtpool
  // Overlays (time-disjoint):
  //   stage-1 bf16 pool (xhi,xlo,Whi,Wlo = SEG floats) over dtb (dead until GEMM3)
  //   stage-4 bf16 pool (yhi,ylo,Wohi,Wolo) over zbuf+xc2 (dead after scan_fix)
  //   y reuses xc_raw (dead after conv)
  const size_t SEG = (size_t)NB * LSEQ * DI;            // 8,388,608
  float* xc_raw = ws;
  float* zbuf   = ws + SEG;
  float* xc2    = ws + 2 * SEG;
  float* dtb    = ws + 3 * SEG;
  float* xp     = ws + 4 * SEG;                         // 393,216
  float* hloc   = xp + (size_t)MROWS * NXP;             // 2,097,152
  float* totdt  = hloc + (size_t)NB * CHUNKS * DSTATE * DI;  // 131,072
  float* dtpool = totdt + (size_t)NB * CHUNKS * DI;

  unsigned short* xhi = (unsigned short*)dtb;
  unsigned short* xlo = xhi + (size_t)MROWS * DMODEL;
  unsigned short* Whi = xlo + (size_t)MROWS * DMODEL;
  unsigned short* Wlo = Whi + (size_t)2 * DI * DMODEL;

  unsigned short* yhi  = (unsigned short*)zbuf;
  unsigned short* ylo  = yhi + SEG;
  unsigned short* Wohi = ylo + SEG;
  unsigned short* Wolo = Wohi + (size_t)DMODEL * DI;

  unsigned short* dthi = (unsigned short*)dtpool;       // 262,144
  unsigned short* dtlo = dthi + (size_t)MROWS * DTRANK;
  unsigned short* wdhi = dtlo + (size_t)MROWS * DTRANK; // 131,072
  unsigned short* wdlo = wdhi + (size_t)DI * DTRANK;

  float* yb = xc_raw;
  dim3 blk(256);

  // Convert x and W_in to bf16 hi/lo
  split_bf16_kernel<<<(MROWS*DMODEL/4 + 255)/256, blk, 0, stream>>>(x, xhi, xlo, MROWS*DMODEL/4);
  split_bf16_kernel<<<(2*DI*DMODEL/4 + 255)/256, blk, 0, stream>>>(W_in, Whi, Wlo, 2*DI*DMODEL/4);

  // GEMM1 fused: [xc | z] = x @ W_in^T  (M=4096, N=4096 over two C buffers, K=1024)
  gemm_bf16x3<false,0><<<dim3(2*DI/128, MROWS/128, 1), blk, 0, stream>>>(
      xhi, xlo, Whi, Wlo, nullptr, xc_raw, zbuf, DI, DMODEL, DMODEL);

  // conv + bias + SiLU
  conv_silu_kernel<<<(NB*LSEQ*DI)/256, blk, 0, stream>>>(xc_raw, conv_w, conv_b, xc2);

  // GEMM2: xp = xc2 @ W_xproj^T  (N=96) — split-K=8 fp32, atomic accumulate
  hipMemsetAsync(xp, 0, (size_t)MROWS * NXP * sizeof(float), stream);
  gemm_nt_splitk<<<dim3(1, MROWS/128, 8), blk, 0, stream>>>(
      xc2, W_xproj, xp, NXP, DI, DI, NXP, DI/8);

  // GEMM3 (MFMA): dt = softplus(dt_lr @ W_dt^T + b_dt)  (M=4096,N=2048,K=64)
  split_dtlr_kernel<<<(MROWS*DTRANK/4)/256, blk, 0, stream>>>(xp, dthi, dtlo);
  split_bf16_kernel<<<(DI*DTRANK/4 + 255)/256, blk, 0, stream>>>(W_dt, wdhi, wdlo, DI*DTRANK/4);
  gemm_bf16x3<false,1><<<dim3(DI/128, MROWS/128, 1), blk, 0, stream>>>(
      dthi, dtlo, wdhi, wdlo, b_dt, dtb, dtb, DI, DTRANK, DTRANK);

  // Chunked scan -> yb
  scan_chunk_kernel<<<dim3(DI/256, NB, CHUNKS), blk, 0, stream>>>(
      xc2, dtb, xp, A_log, yb, hloc, totdt);
  scan_carry_kernel<<<(NB*DI*DSTATE)/256, blk, 0, stream>>>(hloc, totdt, A_log);
  scan_fix_kernel<<<(NB*LSEQ*DI)/256, blk, 0, stream>>>(
      xc2, dtb, xp, zbuf, A_log, Dp, hloc, yb);

  // Convert y and W_out; GEMM4: out = y @ W_out^T — split-K=2, atomic epilogue
  split_bf16_kernel<<<(NB*LSEQ*DI/4 + 255)/256, blk, 0, stream>>>(yb, yhi, ylo, NB*LSEQ*DI/4);
  split_bf16_kernel<<<(DMODEL*DI/4 + 255)/256, blk, 0, stream>>>(W_out, Wohi, Wolo, DMODEL*DI/4);
  hipMemsetAsync(out, 0, (size_t)MROWS * DMODEL * sizeof(float), stream);
  gemm_bf16x3<true,0><<<dim3(DMODEL/128, MROWS/128, 2), blk, 0, stream>>>(
      yhi, ylo, Wohi, Wolo, nullptr, out, out, DMODEL, DI, DI/2);
}

// Round 9
// 590.181 us; speedup vs baseline: 3.8838x; 1.0200x over previous
//
#include <hip/hip_runtime.h>
#include <cstddef>
#include <cstdint>

// Problem constants (match reference)
#define DMODEL 1024
#define DI     2048      // D_INNER
#define LSEQ   2048
#define NB     2
#define DSTATE 16
#define DTRANK 64
#define NXP    96        // DT_RANK + 2*D_STATE
#define MROWS  (NB*LSEQ) // 4096 GEMM rows
#define CHUNKS 32
#define LC     (LSEQ/CHUNKS)   // 64

typedef __attribute__((ext_vector_type(8))) short bf16x8;
typedef __attribute__((ext_vector_type(8))) unsigned short u16x8;
typedef __attribute__((ext_vector_type(4))) float f32x4;

__device__ __forceinline__ float silu_f(float v) {
  return v / (1.f + __expf(-v));
}
__device__ __forceinline__ float softplus_f(float v) {
  return (v > 20.f) ? v : log1pf(__expf(v));
}
__device__ __forceinline__ unsigned short f2bf(float f) {   // RNE
  unsigned u = __float_as_uint(f);
  unsigned r = (u + 0x7FFFu + ((u >> 16) & 1u)) >> 16;
  return (unsigned short)r;
}
__device__ __forceinline__ float bf2f(unsigned short h) {
  return __uint_as_float(((unsigned)h) << 16);
}
__device__ __forceinline__ void gl2lds16(const void* g, void* l) {
  __builtin_amdgcn_global_load_lds(
      (const __attribute__((address_space(1))) void*)g,
      (__attribute__((address_space(3))) void*)l, 16, 0, 0);
}

// Prep: split W_in/W_dt/W_out to bf16 hi/lo (RNE) + zero xp and out.
// One dispatch; block ranges select the job.
__global__ __launch_bounds__(256)
void prep_kernel(const float* __restrict__ W_in, const float* __restrict__ W_dt,
                 const float* __restrict__ W_out,
                 unsigned short* __restrict__ Whi, unsigned short* __restrict__ Wlo,
                 unsigned short* __restrict__ wdhi, unsigned short* __restrict__ wdlo,
                 unsigned short* __restrict__ Wohi, unsigned short* __restrict__ Wolo,
                 float* __restrict__ xp, float* __restrict__ out) {
  const int N_WIN  = 2*DI*DMODEL/4;   // 1,048,576 float4
  const int N_WDT  = DI*DTRANK/4;     //    32,768
  const int N_WOUT = DMODEL*DI/4;     //   524,288
  const int N_XP   = MROWS*NXP/4;     //    98,304
  const int N_OUT  = MROWS*DMODEL/4;  // 1,048,576
  int i = blockIdx.x * 256 + threadIdx.x;
  const float* src = nullptr;
  unsigned short *hi = nullptr, *lo = nullptr;
  if (i < N_WIN)  { src = W_in;  hi = Whi;  lo = Wlo;  }
  else {
    i -= N_WIN;
    if (i < N_WDT)  { src = W_dt;  hi = wdhi; lo = wdlo; }
    else {
      i -= N_WDT;
      if (i < N_WOUT) { src = W_out; hi = Wohi; lo = Wolo; }
      else {
        i -= N_WOUT;
        if (i < N_XP) { ((float4*)xp)[i] = make_float4(0.f,0.f,0.f,0.f); }
        else {
          i -= N_XP;
          if (i < N_OUT) ((float4*)out)[i] = make_float4(0.f,0.f,0.f,0.f);
        }
        return;
      }
    }
  }
  float4 v = ((const float4*)src)[i];
  ushort4 h, l;
  h.x = f2bf(v.x); h.y = f2bf(v.y); h.z = f2bf(v.z); h.w = f2bf(v.w);
  l.x = f2bf(v.x - bf2f(h.x)); l.y = f2bf(v.y - bf2f(h.y));
  l.z = f2bf(v.z - bf2f(h.z)); l.w = f2bf(v.w - bf2f(h.w));
  ((ushort4*)hi)[i] = h; ((ushort4*)lo)[i] = l;
}

// C[m,n] = act( sum_k A[m,k]*B[n,k] ), A fp32 (in-kernel hi/lo split),
// B pre-split bf16 hi/lo. bf16x3: AhBh + AhBl + AlBh.
// 128x128 tile, 4 waves, BK=32, 48 MFMA per barrier pair.
// A: global fp32 loads -> register cvt (truncation split, err 2^-16) ->
//    ds_write_b128 into swizzled layout; next-K A prefetched during MFMA.
// B: global_load_lds 16B, swizzle c' = c ^ ((row>>1)&3) (2-way = free, m136).
// Dual-output cols [0,NC)->C0, [NC,2NC)->C1. Split-K via blockIdx.z.
// ACT=1: softplus(v + bias[col]).
template<bool ATOMIC, int ACT>
__global__ __launch_bounds__(256)
void gemm_a32_bf16x3(const float* __restrict__ A, int lda,
                     const unsigned short* __restrict__ Bhi, const unsigned short* __restrict__ Blo,
                     const float* __restrict__ bias,
                     float* __restrict__ C0, float* __restrict__ C1,
                     int NC, int K, int klen) {
  __shared__ __align__(16) unsigned short Ah[128 * 32];
  __shared__ __align__(16) unsigned short Al[128 * 32];
  __shared__ __align__(16) unsigned short Bh[128 * 32];
  __shared__ __align__(16) unsigned short Bl[128 * 32];
  const int tid  = threadIdx.x;
  const int lane = tid & 63;
  const int wv   = tid >> 6;
  const int wm   = wv >> 1, wn = wv & 1;
  const int quad = lane >> 4, lr = lane & 15;
  const int bm = blockIdx.y * 128, bn = blockIdx.x * 128;
  const int kbeg = blockIdx.z * klen, kend = kbeg + klen;

  // A staging: thread -> (row ar, k-half ahalf); writes 2 granules/plane.
  const int ar = tid >> 1;            // 0..127
  const int ahalf = tid & 1;          // k offset 16*ahalf
  const int asw = (ar >> 1) & 3;
  const int aw0 = (ar * 4 + ((ahalf * 2)     ^ asw)) << 4;   // LDS bytes
  const int aw1 = (ar * 4 + ((ahalf * 2 + 1) ^ asw)) << 4;
  const float* aptr = A + (size_t)(bm + ar) * lda + ahalf * 16;

  // B staging decode
  int bOff[2], ldsO[2];
  #pragma unroll
  for (int j = 0; j < 2; ++j) {
    const int s   = (wv * 2 + j) * 64 + lane;
    const int row = s >> 2;
    const int c   = (s & 3) ^ ((row >> 1) & 3);
    bOff[j] = (bn + row) * K + c * 8;
    ldsO[j] = (wv * 2 + j) << 10;
  }
  // Fragment read byte offsets (swizzle-matched)
  int aRd[4], bRd[4];
  #pragma unroll
  for (int i = 0; i < 4; ++i) {
    const int ra = wm * 64 + i * 16 + lr;
    aRd[i] = (ra * 4 + (quad ^ ((ra >> 1) & 3))) << 4;
    const int rb = wn * 64 + i * 16 + lr;
    bRd[i] = (rb * 4 + (quad ^ ((rb >> 1) & 3))) << 4;
  }

  f32x4 acc[4][4];
  #pragma unroll
  for (int i = 0; i < 4; ++i)
    #pragma unroll
    for (int j = 0; j < 4; ++j)
      acc[i][j] = (f32x4){0.f, 0.f, 0.f, 0.f};

  // Prologue: load first A block (16 fp32 per thread)
  float ac[16], an[16];
  #pragma unroll
  for (int q = 0; q < 4; ++q)
    *(float4*)&ac[q * 4] = *(const float4*)(aptr + kbeg + q * 4);

  #pragma unroll 1
  for (int km = kbeg; km < kend; km += 32) {
    // B async staging
    #pragma unroll
    for (int j = 0; j < 2; ++j) {
      gl2lds16(Bhi + (size_t)bOff[j] + km, (char*)Bh + ldsO[j]);
      gl2lds16(Blo + (size_t)bOff[j] + km, (char*)Bl + ldsO[j]);
    }
    // Prefetch next A block (in flight across the barrier/MFMA phase)
    if (km + 32 < kend) {
      #pragma unroll
      for (int q = 0; q < 4; ++q)
        *(float4*)&an[q * 4] = *(const float4*)(aptr + km + 32 + q * 4);
    }
    // Convert current A -> hi/lo, write to LDS (truncation split)
    u16x8 vh[2], vl[2];
    #pragma unroll
    for (int g = 0; g < 2; ++g)
      #pragma unroll
      for (int e = 0; e < 8; ++e) {
        const float v = ac[g * 8 + e];
        const unsigned u = __float_as_uint(v);
        const float rem = v - __uint_as_float(u & 0xFFFF0000u);
        vh[g][e] = (unsigned short)(u >> 16);
        vl[g][e] = (unsigned short)(__float_as_uint(rem) >> 16);
      }
    *(u16x8*)((char*)Ah + aw0) = vh[0];
    *(u16x8*)((char*)Ah + aw1) = vh[1];
    *(u16x8*)((char*)Al + aw0) = vl[0];
    *(u16x8*)((char*)Al + aw1) = vl[1];
    __syncthreads();

    bf16x8 ah[4], al[4], bh[4], bl[4];
    #pragma unroll
    for (int i = 0; i < 4; ++i) {
      ah[i] = *(const bf16x8*)((const char*)Ah + aRd[i]);
      al[i] = *(const bf16x8*)((const char*)Al + aRd[i]);
      bh[i] = *(const bf16x8*)((const char*)Bh + bRd[i]);
      bl[i] = *(const bf16x8*)((const char*)Bl + bRd[i]);
    }
    #pragma unroll
    for (int i = 0; i < 4; ++i)
      #pragma unroll
      for (int j = 0; j < 4; ++j) {
        acc[i][j] = __builtin_amdgcn_mfma_f32_16x16x32_bf16(ah[i], bh[j], acc[i][j], 0, 0, 0);
        acc[i][j] = __builtin_amdgcn_mfma_f32_16x16x32_bf16(ah[i], bl[j], acc[i][j], 0, 0, 0);
        acc[i][j] = __builtin_amdgcn_mfma_f32_16x16x32_bf16(al[i], bh[j], acc[i][j], 0, 0, 0);
      }
    __syncthreads();
    #pragma unroll
    for (int e = 0; e < 16; ++e) ac[e] = an[e];
  }

  float* C = C0;
  int bnc = bn;
  if (bn >= NC) { C = C1; bnc = bn - NC; }

  // Epilogue: C/D layout col=lane&15, row=quad*4+reg  [m89-verified]
  #pragma unroll
  for (int i = 0; i < 4; ++i) {
    const int gr = bm + wm * 64 + i * 16 + quad * 4;
    #pragma unroll
    for (int j = 0; j < 4; ++j) {
      const int gc = bnc + wn * 64 + j * 16 + lr;
      float* cp = C + (size_t)gr * NC + gc;
      const float bv = (ACT == 1) ? bias[gc] : 0.f;
      #pragma unroll
      for (int r = 0; r < 4; ++r) {
        float v = acc[i][j][r];
        if (ACT == 1) v = softplus_f(v + bv);
        if (ATOMIC) atomicAdd(&cp[(size_t)r * NC], v);
        else        cp[(size_t)r * NC] = v;
      }
    }
  }
}

// Split-K fp32 GEMM, atomicAdd epilogue (C pre-zeroed). Used for GEMM2 (N=96).
__global__ __launch_bounds__(256)
void gemm_nt_splitk(const float* __restrict__ A, const float* __restrict__ B,
                    float* __restrict__ C,
                    int N, int lda, int ldb, int ldc, int kslice) {
  __shared__ float As[16][132];
  __shared__ float Bs[16][132];
  const int tid = threadIdx.x;
  const int bm = blockIdx.y * 128, bn = blockIdx.x * 128;
  const int kbeg = blockIdx.z * kslice, kend = kbeg + kslice;
  const int r  = tid >> 2;
  const int c4 = (tid & 3) << 2;
  const int ty = tid >> 4, tx = tid & 15;
  float acc[8][8];
  #pragma unroll
  for (int i = 0; i < 8; ++i)
    #pragma unroll
    for (int j = 0; j < 8; ++j) acc[i][j] = 0.f;

  for (int k0 = kbeg; k0 < kend; k0 += 16) {
    float4 a0 = *(const float4*)(A + (size_t)(bm + r) * lda + k0 + c4);
    float4 a1 = *(const float4*)(A + (size_t)(bm + r + 64) * lda + k0 + c4);
    float4 b0 = make_float4(0.f, 0.f, 0.f, 0.f);
    float4 b1 = make_float4(0.f, 0.f, 0.f, 0.f);
    if (bn + r < N)      b0 = *(const float4*)(B + (size_t)(bn + r) * ldb + k0 + c4);
    if (bn + r + 64 < N) b1 = *(const float4*)(B + (size_t)(bn + r + 64) * ldb + k0 + c4);
    As[c4+0][r]    = a0.x; As[c4+1][r]    = a0.y; As[c4+2][r]    = a0.z; As[c4+3][r]    = a0.w;
    As[c4+0][r+64] = a1.x; As[c4+1][r+64] = a1.y; As[c4+2][r+64] = a1.z; As[c4+3][r+64] = a1.w;
    Bs[c4+0][r]    = b0.x; Bs[c4+1][r]    = b0.y; Bs[c4+2][r]    = b0.z; Bs[c4+3][r]    = b0.w;
    Bs[c4+0][r+64] = b1.x; Bs[c4+1][r+64] = b1.y; Bs[c4+2][r+64] = b1.z; Bs[c4+3][r+64] = b1.w;
    __syncthreads();
    #pragma unroll
    for (int k = 0; k < 16; ++k) {
      float4 av0 = *(const float4*)&As[k][ty*4];
      float4 av1 = *(const float4*)&As[k][64 + ty*4];
      float4 bv0 = *(const float4*)&Bs[k][tx*4];
      float4 bv1 = *(const float4*)&Bs[k][64 + tx*4];
      float a[8] = {av0.x, av0.y, av0.z, av0.w, av1.x, av1.y, av1.z, av1.w};
      float b[8] = {bv0.x, bv0.y, bv0.z, bv0.w, bv1.x, bv1.y, bv1.z, bv1.w};
      #pragma unroll
      for (int i = 0; i < 8; ++i)
        #pragma unroll
        for (int j = 0; j < 8; ++j)
          acc[i][j] = fmaf(a[i], b[j], acc[i][j]);
    }
    __syncthreads();
  }
  #pragma unroll
  for (int i = 0; i < 8; ++i) {
    const int m = bm + ty * 4 + (i & 3) + ((i >= 4) ? 64 : 0);
    #pragma unroll
    for (int j = 0; j < 8; ++j) {
      const int n = bn + tx * 4 + (j & 3) + ((j >= 4) ? 64 : 0);
      if (n < N) atomicAdd(&C[(size_t)m * ldc + n], acc[i][j]);
    }
  }
}

// Causal depthwise conv (width 4) + bias + SiLU.  xc2[b,l,d]
__global__ __launch_bounds__(256)
void conv_silu_kernel(const float* __restrict__ xc_raw, const float* __restrict__ cw,
                      const float* __restrict__ cb, float* __restrict__ xc2) {
  const int idx = blockIdx.x * 256 + threadIdx.x;
  const int d = idx & (DI - 1);
  const int l = (idx >> 11) & (LSEQ - 1);
  const int b = idx >> 22;
  float acc = cb[d];
  #pragma unroll
  for (int j = 0; j < 4; ++j) {
    const int ls = l - 3 + j;
    if (ls >= 0)
      acc = fmaf(xc_raw[((size_t)b * LSEQ + ls) * DI + d], cw[d * 4 + j], acc);
  }
  xc2[idx] = silu_f(acc);
}

// ---- Chunked selective scan, serial-state layout ----
__global__ __launch_bounds__(256)
void scan_chunk_kernel(const float* __restrict__ xc2, float* __restrict__ dtb,
                       const float* __restrict__ xp, const float* __restrict__ A_log,
                       float* __restrict__ y_local, float* __restrict__ hloc,
                       float* __restrict__ totdt) {
  __shared__ float sbc[LC][32];   // 8 KB: [t][0:16)=B, [16:32)=C
  const int d = blockIdx.x * 256 + threadIdx.x;
  const int b = blockIdx.y;
  const int c = blockIdx.z;

  float A[DSTATE], h[DSTATE];
  #pragma unroll
  for (int n = 0; n < DSTATE; ++n) {
    A[n] = -__expf(A_log[(size_t)d * DSTATE + n]);
    h[n] = 0.f;
  }

  const float* xpb = xp + ((size_t)b * LSEQ + (size_t)c * LC) * NXP + DTRANK;
  #pragma unroll
  for (int kk = 0; kk < 2; ++kk) {
    const int slot = threadIdx.x + kk * 256;
    const int row = slot >> 3, c4 = (slot & 7) << 2;
    *(float4*)&sbc[row][c4] = *(const float4*)&xpb[(size_t)row * NXP + c4];
  }
  __syncthreads();

  const size_t cbase = ((size_t)b * LSEQ + (size_t)c * LC) * DI + d;
  float cum = 0.f;
  constexpr int U = 4;
  float cdt[U], cx[U];
  #pragma unroll
  for (int u = 0; u < U; ++u) {
    cdt[u] = dtb[cbase + (size_t)u * DI];
    cx[u]  = xc2[cbase + (size_t)u * DI];
  }

  #pragma unroll 1
  for (int g = 0; g < LC; g += U) {
    float ndt[U], nx[U];
    if (g + U < LC) {
      #pragma unroll
      for (int u = 0; u < U; ++u) {
        ndt[u] = dtb[cbase + (size_t)(g + U + u) * DI];
        nx[u]  = xc2[cbase + (size_t)(g + U + u) * DI];
      }
    }
    #pragma unroll
    for (int u = 0; u < U; ++u) {
      const int t = g + u;
      const float dt = cdt[u];
      const float dx = dt * cx[u];
      cum += dt;
      #pragma unroll
      for (int n = 0; n < DSTATE; ++n) {
        const float ab = __expf(dt * A[n]);
        h[n] = fmaf(ab, h[n], dx * sbc[t][n]);
      }
      float p[DSTATE];
      #pragma unroll
      for (int n = 0; n < DSTATE; ++n) p[n] = h[n] * sbc[t][DSTATE + n];
      #pragma unroll
      for (int s = 1; s < DSTATE; s <<= 1)
        #pragma unroll
        for (int n = 0; n < DSTATE; n += 2 * s) p[n] += p[n + s];
      const size_t base = cbase + (size_t)t * DI;
      y_local[base] = p[0];
      dtb[base] = cum;               // overwrite dt with inclusive cumsum
    }
    #pragma unroll
    for (int u = 0; u < U; ++u) { cdt[u] = ndt[u]; cx[u] = nx[u]; }
  }

  const size_t hbase = ((size_t)(b * CHUNKS + c)) * DSTATE * DI + d;
  #pragma unroll
  for (int n = 0; n < DSTATE; ++n) hloc[hbase + (size_t)n * DI] = h[n];
  totdt[((size_t)(b * CHUNKS + c)) * DI + d] = cum;
}

// Pass 2: carry propagation. One thread per (b,n,d); 1-chunk prefetch.
__global__ __launch_bounds__(256)
void scan_carry_kernel(float* __restrict__ hloc, const float* __restrict__ totdt,
                       const float* __restrict__ A_log) {
  const int tid = blockIdx.x * 256 + threadIdx.x;   // NB*DSTATE*DI
  const int d = tid & (DI - 1);
  const int n = (tid >> 11) & 15;
  const int b = tid >> 15;
  const float An = -__expf(A_log[(size_t)d * DSTATE + n]);
  float h = 0.f;
  float le = hloc[((size_t)(b * CHUNKS) * DSTATE + n) * DI + d];
  float td = totdt[(size_t)(b * CHUNKS) * DI + d];
  for (int c = 0; c < CHUNKS; ++c) {
    const size_t ix = ((size_t)(b * CHUNKS + c) * DSTATE + n) * DI + d;
    float nle = 0.f, ntd = 0.f;
    if (c + 1 < CHUNKS) {
      nle = hloc[ix + (size_t)DSTATE * DI];
      ntd = totdt[(size_t)(b * CHUNKS + c + 1) * DI + d];
    }
    hloc[ix] = h;
    h = fmaf(__expf(An * td), h, le);
    le = nle; td = ntd;
  }
}

// Pass 3: correction + epilogue.  hloc layout [b][c][n][d].
__global__ __launch_bounds__(256)
void scan_fix_kernel(const float* __restrict__ xc2, const float* __restrict__ dtb,
                     const float* __restrict__ xp, const float* __restrict__ zbuf,
                     const float* __restrict__ A_log, const float* __restrict__ Dp,
                     const float* __restrict__ hloc, float* __restrict__ y) {
  __shared__ float sA[256 * DSTATE];
  const int tid = threadIdx.x;
  const int idx = blockIdx.x * 256 + tid;
  const int d = idx & (DI - 1);
  const int l = (idx >> 11) & (LSEQ - 1);
  const int b = idx >> 22;
  const int d0 = (blockIdx.x & ((DI / 256) - 1)) * 256;
  for (int i = tid; i < 256 * DSTATE; i += 256)
    sA[i] = -__expf(A_log[(size_t)d0 * DSTATE + i]);
  __syncthreads();

  const int c = l / LC;
  const float cum = dtb[idx];
  const float* hp = hloc + ((size_t)(b * CHUNKS + c)) * DSTATE * DI + d;
  const float4* Ct4 = (const float4*)&xp[((size_t)b * LSEQ + l) * NXP + DTRANK + DSTATE];
  const float* Ar = &sA[(d - d0) * DSTATE];
  float Ct[DSTATE];
  #pragma unroll
  for (int q = 0; q < 4; ++q) {
    const float4 cv = Ct4[q];
    Ct[4*q+0] = cv.x; Ct[4*q+1] = cv.y; Ct[4*q+2] = cv.z; Ct[4*q+3] = cv.w;
  }
  float corr = 0.f;
  #pragma unroll
  for (int n = 0; n < DSTATE; ++n)
    corr = fmaf(__expf(Ar[n] * cum) * hp[(size_t)n * DI], Ct[n], corr);
  const float xv = xc2[idx], zv = zbuf[idx];
  y[idx] = (y[idx] + corr + xv * Dp[d]) * silu_f(zv);
}

extern "C" void kernel_launch(void* const* d_in, const int* in_sizes, int n_in,
                              void* d_out, int out_size, void* d_ws, size_t ws_size,
                              hipStream_t stream) {
  const float* x      = (const float*)d_in[0];
  const float* W_in   = (const float*)d_in[1];
  const float* conv_w = (const float*)d_in[2];
  const float* conv_b = (const float*)d_in[3];
  const float* W_xproj= (const float*)d_in[4];
  const float* W_dt   = (const float*)d_in[5];
  const float* b_dt   = (const float*)d_in[6];
  const float* A_log  = (const float*)d_in[7];
  const float* Dp     = (const float*)d_in[8];
  const float* W_out  = (const float*)d_in[9];
  float* out = (float*)d_out;
  float* ws  = (float*)d_ws;

  // ws layout (floats), ~154 MB:
  //   xc_raw[SEG] | zbuf[SEG] | xc2[SEG] | dtb[SEG] | xp | hloc | totdt | Wo/Wd pools
  // Overlays (time-disjoint): Whi/Wlo (4.2M floats) over dtb — consumed by
  // GEMM1, dtb first written by GEMM3 afterwards. y reuses xc_raw.
  const size_t SEG = (size_t)NB * LSEQ * DI;            // 8,388,608
  float* xc_raw = ws;
  float* zbuf   = ws + SEG;
  float* xc2    = ws + 2 * SEG;
  float* dtb    = ws + 3 * SEG;
  float* xp     = ws + 4 * SEG;                         // 393,216
  float* hloc   = xp + (size_t)MROWS * NXP;             // 2,097,152
  float* totdt  = hloc + (size_t)NB * CHUNKS * DSTATE * DI;  // 131,072
  float* wpool  = totdt + (size_t)NB * CHUNKS * DI;

  unsigned short* Whi = (unsigned short*)dtb;           // overlay (dead until GEMM3)
  unsigned short* Wlo = Whi + (size_t)2 * DI * DMODEL;

  unsigned short* Wohi = (unsigned short*)wpool;        // 2,097,152 ushort
  unsigned short* Wolo = Wohi + (size_t)DMODEL * DI;
  unsigned short* wdhi = Wolo + (size_t)DMODEL * DI;    // 131,072 ushort
  unsigned short* wdlo = wdhi + (size_t)DI * DTRANK;

  float* yb = xc_raw;
  dim3 blk(256);

  // Prep: weight splits + zero xp/out (one dispatch)
  const int prep_blocks = (2*DI*DMODEL/4 + DI*DTRANK/4 + DMODEL*DI/4
                           + MROWS*NXP/4 + MROWS*DMODEL/4) / 256;
  prep_kernel<<<prep_blocks, blk, 0, stream>>>(
      W_in, W_dt, W_out, Whi, Wlo, wdhi, wdlo, Wohi, Wolo, xp, out);

  // GEMM1 fused: [xc | z] = x @ W_in^T  (A=x fp32 in-kernel split; K=1024)
  gemm_a32_bf16x3<false,0><<<dim3(2*DI/128, MROWS/128, 1), blk, 0, stream>>>(
      x, DMODEL, Whi, Wlo, nullptr, xc_raw, zbuf, DI, DMODEL, DMODEL);

  // conv + bias + SiLU
  conv_silu_kernel<<<(NB*LSEQ*DI)/256, blk, 0, stream>>>(xc_raw, conv_w, conv_b, xc2);

  // GEMM2: xp = xc2 @ W_xproj^T  (N=96) — split-K=8 fp32, atomic (xp zeroed in prep)
  gemm_nt_splitk<<<dim3(1, MROWS/128, 8), blk, 0, stream>>>(
      xc2, W_xproj, xp, NXP, DI, DI, NXP, DI/8);

  // GEMM3: dt = softplus(dt_lr @ W_dt^T + b_dt)  (A = xp[:, 0:64], lda=96, K=64)
  gemm_a32_bf16x3<false,1><<<dim3(DI/128, MROWS/128, 1), blk, 0, stream>>>(
      xp, NXP, wdhi, wdlo, b_dt, dtb, dtb, DI, DTRANK, DTRANK);

  // Chunked scan -> yb
  scan_chunk_kernel<<<dim3(DI/256, NB, CHUNKS), blk, 0, stream>>>(
      xc2, dtb, xp, A_log, yb, hloc, totdt);
  scan_carry_kernel<<<(NB*DI*DSTATE)/256, blk, 0, stream>>>(hloc, totdt, A_log);
  scan_fix_kernel<<<(NB*LSEQ*DI)/256, blk, 0, stream>>>(
      xc2, dtb, xp, zbuf, A_log, Dp, hloc, yb);

  // GEMM4: out = y @ W_out^T — A=y fp32 in-kernel split; split-K=2, atomic
  // (out zeroed in prep)
  gemm_a32_bf16x3<true,0><<<dim3(DMODEL/128, MROWS/128, 2), blk, 0, stream>>>(
      yb, DI, Wohi, Wolo, nullptr, out, out, DMODEL, DI, DI/2);
}